// Round 1
// baseline (2590.914 us; speedup 1.0000x reference)
//
#include <hip/hip_runtime.h>
#include <hip/hip_bf16.h>

#define THREADS 256
#define GRU_ROWS 32

static inline size_t align_up(size_t x, size_t a) { return (x + a - 1) & ~(a - 1); }

// ---------- detect whether index inputs are stored as int64 (low/high words) ----------
__global__ void k_detect(const int* __restrict__ ei, int* __restrict__ flag) {
  if (blockIdx.x == 0 && threadIdx.x == 0) {
    int odd_zero = ((ei[1] | ei[3] | ei[5] | ei[7]) == 0);
    int even_nz  = ((ei[0] | ei[2] | ei[4] | ei[6]) != 0);
    flag[0] = (odd_zero && even_nz) ? 1 : 0;
  }
}

// ---------- Wc[i][j][k] = sum_t weight[i][k][t] * w_ih[j][t]  (3 x 384 x 128) ----------
__global__ void k_wc(const float* __restrict__ weight, const float* __restrict__ w_ih,
                     float* __restrict__ Wc) {
  int idx = blockIdx.x * blockDim.x + threadIdx.x;
  const int total = 3 * 384 * 128;
  if (idx >= total) return;
  int k = idx & 127;
  int j = (idx >> 7) % 384;
  int i = idx / (384 * 128);
  const float* wp = weight + (size_t)i * (128 * 128) + (size_t)k * 128;
  const float* ip = w_ih + (size_t)j * 128;
  float s = 0.f;
#pragma unroll 8
  for (int t = 0; t < 128; ++t) s += wp[t] * ip[t];
  Wc[idx] = s;
}

// ---------- CSR build ----------
__global__ void k_hist(const int* __restrict__ ei, int* __restrict__ counts,
                       int E, const int* __restrict__ flag) {
  int i = blockIdx.x * blockDim.x + threadIdx.x;
  if (i >= E) return;
  int s64 = flag[0];
  size_t idx = s64 ? 2 * ((size_t)E + (size_t)i) : ((size_t)E + (size_t)i);
  atomicAdd(&counts[ei[idx]], 1);
}

__global__ void k_scan1(const int* __restrict__ counts, int* __restrict__ offs,
                        int* __restrict__ bsum, int n) {
  __shared__ int s[256];
  int b = blockIdx.x, t = threadIdx.x;
  int i = b * 256 + t;
  int v = (i < n) ? counts[i] : 0;
  s[t] = v;
  __syncthreads();
  for (int d = 1; d < 256; d <<= 1) {
    int x = (t >= d) ? s[t - d] : 0;
    __syncthreads();
    s[t] += x;
    __syncthreads();
  }
  if (i < n) offs[i] = s[t] - v;      // exclusive
  if (t == 255) bsum[b] = s[t];       // block total
}

__global__ void k_scan2(int* __restrict__ bsum, int nb) {
  __shared__ int s[512];
  int t = threadIdx.x;
  int v = (t < nb) ? bsum[t] : 0;
  s[t] = v;
  __syncthreads();
  for (int d = 1; d < 512; d <<= 1) {
    int x = (t >= d) ? s[t - d] : 0;
    __syncthreads();
    s[t] += x;
    __syncthreads();
  }
  if (t < nb) bsum[t] = s[t] - v;     // exclusive block prefix
}

__global__ void k_scan3(int* __restrict__ offs, int* __restrict__ cursor,
                        const int* __restrict__ bsum, int n, int total) {
  int i = blockIdx.x * blockDim.x + threadIdx.x;
  if (i < n) {
    int o = offs[i] + bsum[i >> 8];
    offs[i] = o;
    cursor[i] = o;
  }
  if (i == 0) offs[n] = total;
}

__global__ void k_fill(const int* __restrict__ ei, int* __restrict__ cursor,
                       int* __restrict__ csr, int E, const int* __restrict__ flag) {
  int i = blockIdx.x * blockDim.x + threadIdx.x;
  if (i >= E) return;
  int s64 = flag[0];
  int sv = ei[s64 ? 2 * (size_t)i : (size_t)i];
  int dv = ei[s64 ? 2 * ((size_t)E + (size_t)i) : ((size_t)E + (size_t)i)];
  int pos = atomicAdd(&cursor[dv], 1);
  csr[pos] = sv;
}

__global__ void k_bounds(const int* __restrict__ batch, int* __restrict__ gs,
                         int* __restrict__ ge, int n, const int* __restrict__ flag) {
  int i = blockIdx.x * blockDim.x + threadIdx.x;
  if (i >= n) return;
  int s64 = flag[0];
  int b  = batch[s64 ? 2 * (size_t)i : (size_t)i];
  int bp = (i > 0)     ? batch[s64 ? 2 * (size_t)(i - 1) : (size_t)(i - 1)] : -1;
  int bn = (i < n - 1) ? batch[s64 ? 2 * (size_t)(i + 1) : (size_t)(i + 1)] : -1;
  if (i == 0 || bp != b) gs[b] = i;
  if (i == n - 1 || bn != b) ge[b] = i + 1;
}

// ---------- aggregation: agg[n] = sum over in-edges of h[src] (pull via CSR) ----------
__global__ void k_agg(const float* __restrict__ h, const int* __restrict__ offs,
                      const int* __restrict__ csr, float* __restrict__ agg, int n) {
  int node = (blockIdx.x * THREADS + threadIdx.x) >> 6;
  int lane = threadIdx.x & 63;
  if (node >= n) return;
  int s = offs[node], e = offs[node + 1];
  float2 acc = make_float2(0.f, 0.f);
  for (int i = s; i < e; ++i) {
    int srcn = csr[i];
    float2 v = ((const float2*)(h + (size_t)srcn * 128))[lane];
    acc.x += v.x;
    acc.y += v.y;
  }
  ((float2*)(agg + (size_t)node * 128))[lane] = acc;
}

// ---------- fused GRU: h = GRUCell(agg, h) in place ----------
__launch_bounds__(THREADS, 2)
__global__ void k_gru(const float* __restrict__ agg, float* __restrict__ h,
                      const float* __restrict__ Wc, const float* __restrict__ whh,
                      const float* __restrict__ b_ih, const float* __restrict__ b_hh,
                      int n) {
  __shared__ __hip_bfloat16 sA[2][128][GRU_ROWS + 2];   // [agg|h][k][row]
  __shared__ __align__(16) float sW[128][68];           // [k][c], padded
  const int t = threadIdx.x;
  const int row0 = blockIdx.x * GRU_ROWS;

  // stage agg and h tiles transposed to [k][row], bf16
  for (int m = 0; m < 2; ++m) {
    const float* src = m ? h : agg;
    for (int i = t; i < GRU_ROWS * 128; i += THREADS) {
      int r = i >> 7;
      int k = i & 127;
      int row = row0 + r;
      float v = (row < n) ? src[(size_t)row * 128 + k] : 0.f;
      sA[m][k][r] = __float2bfloat16(v);
    }
  }

  const int c0 = 4 * (t & 15);   // 0..60
  const int r0 = 2 * (t >> 4);   // 0..30
  float acc[6][8];

  for (int p = 0; p < 2; ++p) {
#pragma unroll
    for (int g = 0; g < 6; ++g)
#pragma unroll
      for (int j = 0; j < 8; ++j) acc[g][j] = 0.f;

#pragma unroll
    for (int g = 0; g < 6; ++g) {
      const float* Wsrc = (g < 3) ? Wc : whh;
      const int jbase = (g % 3) * 128 + p * 64;
      __syncthreads();
      for (int i = t; i < 64 * 128; i += THREADS) {
        int k = i & 127;
        int c = i >> 7;
        sW[k][c] = Wsrc[(size_t)(jbase + c) * 128 + k];
      }
      __syncthreads();
      const int aId = (g < 3) ? 0 : 1;
#pragma unroll 4
      for (int k = 0; k < 128; ++k) {
        float a0 = __bfloat162float(sA[aId][k][r0]);
        float a1 = __bfloat162float(sA[aId][k][r0 + 1]);
        const float4 w = *(const float4*)&sW[k][c0];
        acc[g][0] += a0 * w.x;  acc[g][1] += a0 * w.y;
        acc[g][2] += a0 * w.z;  acc[g][3] += a0 * w.w;
        acc[g][4] += a1 * w.x;  acc[g][5] += a1 * w.y;
        acc[g][6] += a1 * w.z;  acc[g][7] += a1 * w.w;
      }
    }

    // combine gates -> h (in place; this block owns these rows)
#pragma unroll
    for (int rr = 0; rr < 2; ++rr) {
      int row = row0 + r0 + rr;
      if (row >= n) continue;
#pragma unroll
      for (int cc = 0; cc < 4; ++cc) {
        int col = p * 64 + c0 + cc;
        int j = rr * 4 + cc;
        float ir = acc[0][j] + b_ih[col];
        float iz = acc[1][j] + b_ih[128 + col];
        float in_ = acc[2][j] + b_ih[256 + col];
        float hr = acc[3][j] + b_hh[col];
        float hz = acc[4][j] + b_hh[128 + col];
        float hn = acc[5][j] + b_hh[256 + col];
        float r = 1.f / (1.f + expf(-(ir + hr)));
        float z = 1.f / (1.f + expf(-(iz + hz)));
        float nn = tanhf(in_ + r * hn);
        float hold = h[(size_t)row * 128 + col];
        h[(size_t)row * 128 + col] = (1.f - z) * nn + z * hold;
      }
    }
  }
}

// ---------- per-node 1/max(||h||,eps) ----------
__global__ void k_norm(const float* __restrict__ h, float* __restrict__ rnorm, int n) {
  int node = (blockIdx.x * THREADS + threadIdx.x) >> 6;
  int lane = threadIdx.x & 63;
  if (node >= n) return;
  float2 v = ((const float2*)(h + (size_t)node * 128))[lane];
  float s = v.x * v.x + v.y * v.y;
#pragma unroll
  for (int d = 1; d < 64; d <<= 1) s += __shfl_xor(s, d);
  if (lane == 0) rnorm[node] = 1.f / fmaxf(sqrtf(s), 1e-12f);
}

// ---------- per-graph max/mean pool of relu(h * rnorm) ----------
__global__ void k_pool(const float* __restrict__ h, const float* __restrict__ rnorm,
                       const int* __restrict__ gs, const int* __restrict__ ge,
                       float* __restrict__ feat) {
  int g = blockIdx.x;
  int c = threadIdx.x;  // 128 threads
  int s = gs[g], e = ge[g];
  float mx = 0.f, sm = 0.f;
  for (int nd = s; nd < e; ++nd) {
    float v = h[(size_t)nd * 128 + c] * rnorm[nd];
    v = fmaxf(v, 0.f);
    mx = fmaxf(mx, v);
    sm += v;
  }
  float cnt = fmaxf((float)(e - s), 1.f);
  feat[(size_t)g * 256 + c] = mx;
  feat[(size_t)g * 256 + 128 + c] = sm / cnt;
}

// ---------- final linear: out[g][cls] = feat[g] . lin_w[cls] + lin_b ----------
__global__ void k_final(const float* __restrict__ feat, const float* __restrict__ lin_w,
                        const float* __restrict__ lin_b, float* __restrict__ out) {
  int g = blockIdx.x;
  __shared__ float sf[256];
  sf[threadIdx.x] = feat[(size_t)g * 256 + threadIdx.x];
  __syncthreads();
  if (threadIdx.x < 10) {
    float s = lin_b[threadIdx.x];
    const float* w = lin_w + (size_t)threadIdx.x * 256;
#pragma unroll 8
    for (int c = 0; c < 256; ++c) s += sf[c] * w[c];
    out[(size_t)g * 10 + threadIdx.x] = s;
  }
}

extern "C" void kernel_launch(void* const* d_in, const int* in_sizes, int n_in,
                              void* d_out, int out_size, void* d_ws, size_t ws_size,
                              hipStream_t stream) {
  const float* x      = (const float*)d_in[0];
  const int*   ei     = (const int*)d_in[1];
  const int*   batch  = (const int*)d_in[2];
  const float* weight = (const float*)d_in[3];
  const float* w_ih   = (const float*)d_in[4];
  const float* w_hh   = (const float*)d_in[5];
  const float* b_ih   = (const float*)d_in[6];
  const float* b_hh   = (const float*)d_in[7];
  const float* lin_w  = (const float*)d_in[8];
  const float* lin_b  = (const float*)d_in[9];
  float* out = (float*)d_out;

  const int N = in_sizes[0] / 128;   // 100000
  const int E = in_sizes[1] / 2;     // 1600000
  const int G = out_size / 10;       // 64

  char* wsc = (char*)d_ws;
  size_t off = 0;
  auto take = [&](size_t bytes) -> void* {
    void* p = wsc + off;
    off = align_up(off + bytes, 256);
    return p;
  };
  float* h      = (float*)take((size_t)N * 128 * 4);
  float* agg    = (float*)take((size_t)N * 128 * 4);
  float* Wc     = (float*)take((size_t)3 * 384 * 128 * 4);
  float* rnorm  = (float*)take((size_t)N * 4);
  int*   counts = (int*)take((size_t)N * 4);
  int*   offs   = (int*)take(((size_t)N + 1) * 4);
  int*   cursor = (int*)take((size_t)N * 4);
  int*   bsum   = (int*)take(512 * 4);
  int*   csr    = (int*)take((size_t)E * 4);
  int*   gs     = (int*)take((size_t)G * 4);
  int*   ge     = (int*)take((size_t)G * 4);
  float* feat   = (float*)take((size_t)G * 256 * 4);
  int*   flag   = (int*)take(256);
  (void)ws_size; (void)n_in;

  hipMemcpyAsync(h, x, (size_t)N * 128 * 4, hipMemcpyDeviceToDevice, stream);
  hipMemsetAsync(counts, 0, (size_t)N * 4, stream);
  hipMemsetAsync(gs, 0, (size_t)G * 4, stream);
  hipMemsetAsync(ge, 0, (size_t)G * 4, stream);

  k_detect<<<1, 64, 0, stream>>>(ei, flag);
  k_wc<<<(3 * 384 * 128 + THREADS - 1) / THREADS, THREADS, 0, stream>>>(weight, w_ih, Wc);

  int nb = (N + 255) / 256;
  k_hist<<<(E + THREADS - 1) / THREADS, THREADS, 0, stream>>>(ei, counts, E, flag);
  k_scan1<<<nb, 256, 0, stream>>>(counts, offs, bsum, N);
  k_scan2<<<1, 512, 0, stream>>>(bsum, nb);
  k_scan3<<<nb, 256, 0, stream>>>(offs, cursor, bsum, N, E);
  k_fill<<<(E + THREADS - 1) / THREADS, THREADS, 0, stream>>>(ei, cursor, csr, E, flag);
  k_bounds<<<nb, 256, 0, stream>>>(batch, gs, ge, N, flag);

  for (int layer = 0; layer < 3; ++layer) {
    k_agg<<<(N + 3) / 4, THREADS, 0, stream>>>(h, offs, csr, agg, N);
    k_gru<<<(N + GRU_ROWS - 1) / GRU_ROWS, THREADS, 0, stream>>>(
        agg, h, Wc + (size_t)layer * 384 * 128, w_hh, b_ih, b_hh, N);
  }

  k_norm<<<(N + 3) / 4, THREADS, 0, stream>>>(h, rnorm, N);
  k_pool<<<G, 128, 0, stream>>>(h, rnorm, gs, ge, feat);
  k_final<<<G, 256, 0, stream>>>(feat, lin_w, lin_b, out);
}

// Round 2
// 1037.299 us; speedup vs baseline: 2.4978x; 2.4978x over previous
//
#include <hip/hip_runtime.h>
#include <hip/hip_bf16.h>

#define THREADS 256
#define POOLS 16

typedef __attribute__((ext_vector_type(8))) short bf16x8;
typedef __attribute__((ext_vector_type(4))) float f32x4;

static inline size_t align_up(size_t x, size_t a) { return (x + a - 1) & ~(a - 1); }

// ---------- detect whether index inputs are stored as int64 (low/high words) ----------
__global__ void k_detect(const int* __restrict__ ei, int* __restrict__ flag) {
  if (blockIdx.x == 0 && threadIdx.x == 0) {
    int odd_zero = ((ei[1] | ei[3] | ei[5] | ei[7]) == 0);
    int even_nz  = ((ei[0] | ei[2] | ei[4] | ei[6]) != 0);
    flag[0] = (odd_zero && even_nz) ? 1 : 0;
  }
}

// ---------- Wc[i][j][k] = sum_t weight[i][k][t] * w_ih[j][t]  (3 x 384 x 128) ----------
__global__ void k_wc(const float* __restrict__ weight, const float* __restrict__ w_ih,
                     float* __restrict__ Wc) {
  int idx = blockIdx.x * blockDim.x + threadIdx.x;
  const int total = 3 * 384 * 128;
  if (idx >= total) return;
  int k = idx & 127;
  int j = (idx >> 7) % 384;
  int i = idx / (384 * 128);
  const float* wp = weight + (size_t)i * (128 * 128) + (size_t)k * 128;
  const float* ip = w_ih + (size_t)j * 128;
  float s = 0.f;
#pragma unroll 8
  for (int t = 0; t < 128; ++t) s += wp[t] * ip[t];
  Wc[idx] = s;
}

// ---------- pack weights into MFMA fragment-major bf16 layout ----------
// Wp[layer][g(6)][ct(8)][ks(4)][lane(64)][j(8)]
//   row = (g%3)*128 + ct*16 + (lane&15);  k = ks*32 + (lane>>4)*8 + j
//   g<3 -> Wc[layer], g>=3 -> w_hh
__global__ void k_wprep(const float* __restrict__ Wc, const float* __restrict__ whh,
                        __hip_bfloat16* __restrict__ Wp) {
  int idx = blockIdx.x * blockDim.x + threadIdx.x;
  const int per_layer = 6 * 8 * 4 * 64 * 8;  // 98304
  if (idx >= 3 * per_layer) return;
  int layer = idx / per_layer;
  int rem = idx % per_layer;
  int j    = rem & 7;
  int lane = (rem >> 3) & 63;
  int ks   = (rem >> 9) & 3;
  int ct   = (rem >> 11) & 7;
  int g    = rem >> 14;  // 0..5
  int row = (g % 3) * 128 + ct * 16 + (lane & 15);
  int k   = ks * 32 + (lane >> 4) * 8 + j;
  float v = (g < 3) ? Wc[(size_t)layer * 384 * 128 + (size_t)row * 128 + k]
                    : whh[(size_t)row * 128 + k];
  Wp[idx] = __float2bfloat16(v);
}

// ---------- h = x (f32), hb = bf16(x) ----------
__global__ void k_init(const float* __restrict__ x, float* __restrict__ h,
                       __hip_bfloat16* __restrict__ hb, int total4) {
  int i = blockIdx.x * blockDim.x + threadIdx.x;
  if (i >= total4) return;
  float4 v = ((const float4*)x)[i];
  ((float4*)h)[i] = v;
  __hip_bfloat162 a, b;
  a.x = __float2bfloat16(v.x); a.y = __float2bfloat16(v.y);
  b.x = __float2bfloat16(v.z); b.y = __float2bfloat16(v.w);
  ((__hip_bfloat162*)hb)[2 * i]     = a;
  ((__hip_bfloat162*)hb)[2 * i + 1] = b;
}

// ---------- CSR build ----------
__global__ void k_hist(const int* __restrict__ ei, int* __restrict__ counts,
                       int E, const int* __restrict__ flag) {
  int i = blockIdx.x * blockDim.x + threadIdx.x;
  if (i >= E) return;
  int s64 = flag[0];
  size_t idx = s64 ? 2 * ((size_t)E + (size_t)i) : ((size_t)E + (size_t)i);
  atomicAdd(&counts[ei[idx]], 1);
}

__global__ void k_scan1(const int* __restrict__ counts, int* __restrict__ offs,
                        int* __restrict__ bsum, int n) {
  __shared__ int s[256];
  int b = blockIdx.x, t = threadIdx.x;
  int i = b * 256 + t;
  int v = (i < n) ? counts[i] : 0;
  s[t] = v;
  __syncthreads();
  for (int d = 1; d < 256; d <<= 1) {
    int x = (t >= d) ? s[t - d] : 0;
    __syncthreads();
    s[t] += x;
    __syncthreads();
  }
  if (i < n) offs[i] = s[t] - v;
  if (t == 255) bsum[b] = s[t];
}

__global__ void k_scan2(int* __restrict__ bsum, int nb) {
  __shared__ int s[512];
  int t = threadIdx.x;
  int v = (t < nb) ? bsum[t] : 0;
  s[t] = v;
  __syncthreads();
  for (int d = 1; d < 512; d <<= 1) {
    int x = (t >= d) ? s[t - d] : 0;
    __syncthreads();
    s[t] += x;
    __syncthreads();
  }
  if (t < nb) bsum[t] = s[t] - v;
}

__global__ void k_scan3(int* __restrict__ offs, int* __restrict__ cursor,
                        const int* __restrict__ bsum, int n, int total) {
  int i = blockIdx.x * blockDim.x + threadIdx.x;
  if (i < n) {
    int o = offs[i] + bsum[i >> 8];
    offs[i] = o;
    cursor[i] = o;
  }
  if (i == 0) offs[n] = total;
}

__global__ void k_fill(const int* __restrict__ ei, int* __restrict__ cursor,
                       int* __restrict__ csr, int E, const int* __restrict__ flag) {
  int i = blockIdx.x * blockDim.x + threadIdx.x;
  if (i >= E) return;
  int s64 = flag[0];
  int sv = ei[s64 ? 2 * (size_t)i : (size_t)i];
  int dv = ei[s64 ? 2 * ((size_t)E + (size_t)i) : ((size_t)E + (size_t)i)];
  int pos = atomicAdd(&cursor[dv], 1);
  csr[pos] = sv;
}

__global__ void k_bounds(const int* __restrict__ batch, int* __restrict__ gs,
                         int* __restrict__ ge, int n, const int* __restrict__ flag) {
  int i = blockIdx.x * blockDim.x + threadIdx.x;
  if (i >= n) return;
  int s64 = flag[0];
  int b  = batch[s64 ? 2 * (size_t)i : (size_t)i];
  int bp = (i > 0)     ? batch[s64 ? 2 * (size_t)(i - 1) : (size_t)(i - 1)] : -1;
  int bn = (i < n - 1) ? batch[s64 ? 2 * (size_t)(i + 1) : (size_t)(i + 1)] : -1;
  if (i == 0 || bp != b) gs[b] = i;
  if (i == n - 1 || bn != b) ge[b] = i + 1;
}

// ---------- aggregation: agg[n] = sum over in-edges of hb[src] (pull via CSR) ----------
__global__ void k_agg(const __hip_bfloat16* __restrict__ hb, const int* __restrict__ offs,
                      const int* __restrict__ csr, __hip_bfloat16* __restrict__ agg, int n) {
  int node = (blockIdx.x * THREADS + threadIdx.x) >> 6;
  int lane = threadIdx.x & 63;
  if (node >= n) return;
  int s = offs[node], e = offs[node + 1];
  float ax = 0.f, ay = 0.f;
  for (int i = s; i < e; ++i) {
    int srcn = csr[i];
    __hip_bfloat162 v = *(const __hip_bfloat162*)(hb + (size_t)srcn * 128 + lane * 2);
    ax += __bfloat162float(v.x);
    ay += __bfloat162float(v.y);
  }
  __hip_bfloat162 o;
  o.x = __float2bfloat16(ax);
  o.y = __float2bfloat16(ay);
  *(__hip_bfloat162*)(agg + (size_t)node * 128 + lane * 2) = o;
}

// ---------- fused MFMA GRU: h = GRUCell(agg, h) in place; hb mirrors h in bf16 ----------
// block: 256 threads = 4 waves; 32 rows x 128 cols; wave wc owns cols [wc*32, wc*32+32)
__launch_bounds__(256, 2)
__global__ void k_gru_mfma(const __hip_bfloat16* __restrict__ agg,
                           float* __restrict__ h,
                           __hip_bfloat16* __restrict__ hb,
                           const __hip_bfloat16* __restrict__ Wp,  // layer slice, frag-major
                           const float* __restrict__ b_ih,
                           const float* __restrict__ b_hh,
                           int n) {
  __shared__ __align__(16) __hip_bfloat16 sA[2][32][128];  // [agg|h][row][k] chunk-swizzled
  const int t = threadIdx.x;
  const int lane = t & 63;
  const int wc = t >> 6;
  const int row0 = blockIdx.x * 32;

  // stage A: 2 matrices x 32 rows x 16 chunks(16B); chunk-XOR swizzle vs bank conflicts
  for (int i = t; i < 2 * 32 * 16; i += 256) {
    int m   = i >> 9;
    int row = (i >> 4) & 31;
    int c   = i & 15;
    int gr  = row0 + row;
    uint4 v = make_uint4(0u, 0u, 0u, 0u);
    const __hip_bfloat16* src = m ? hb : agg;
    if (gr < n) v = *(const uint4*)(src + (size_t)gr * 128 + c * 8);
    *(uint4*)(&sA[m][row][(c ^ (row & 7)) * 8]) = v;
  }
  __syncthreads();

  f32x4 acc[6][2][2];
#pragma unroll
  for (int g = 0; g < 6; ++g)
#pragma unroll
    for (int mt = 0; mt < 2; ++mt)
#pragma unroll
      for (int nt = 0; nt < 2; ++nt)
        acc[g][mt][nt] = (f32x4){0.f, 0.f, 0.f, 0.f};

  const int nrow = lane & 15;
  const int kgrp = lane >> 4;

  for (int ks = 0; ks < 4; ++ks) {
    bf16x8 af[2][2];
#pragma unroll
    for (int m = 0; m < 2; ++m)
#pragma unroll
      for (int mt = 0; mt < 2; ++mt) {
        int row = mt * 16 + nrow;
        int kc  = ks * 4 + kgrp;
        af[m][mt] = *(const bf16x8*)(&sA[m][row][(kc ^ (row & 7)) * 8]);
      }
    bf16x8 bfr[6][2];
#pragma unroll
    for (int g = 0; g < 6; ++g)
#pragma unroll
      for (int nt = 0; nt < 2; ++nt) {
        size_t boff = ((((size_t)g * 8 + (wc * 2 + nt)) * 4 + (size_t)ks) * 64 + lane) * 8;
        bfr[g][nt] = *(const bf16x8*)(Wp + boff);
      }
#pragma unroll
    for (int g = 0; g < 6; ++g)
#pragma unroll
      for (int mt = 0; mt < 2; ++mt)
#pragma unroll
        for (int nt = 0; nt < 2; ++nt)
          acc[g][mt][nt] = __builtin_amdgcn_mfma_f32_16x16x32_bf16(
              af[g < 3 ? 0 : 1][mt], bfr[g][nt], acc[g][mt][nt], 0, 0, 0);
  }

  // epilogue: gates -> h (f32, in place) + hb (bf16 mirror)
#pragma unroll
  for (int nt = 0; nt < 2; ++nt) {
    int col = wc * 32 + nt * 16 + nrow;
    float bir = b_ih[col], biz = b_ih[128 + col], bin = b_ih[256 + col];
    float bhr = b_hh[col], bhz = b_hh[128 + col], bhn = b_hh[256 + col];
#pragma unroll
    for (int mt = 0; mt < 2; ++mt) {
#pragma unroll
      for (int j = 0; j < 4; ++j) {
        int row = row0 + mt * 16 + kgrp * 4 + j;
        if (row >= n) continue;
        float ir  = acc[0][mt][nt][j] + bir;
        float iz  = acc[1][mt][nt][j] + biz;
        float in_ = acc[2][mt][nt][j] + bin;
        float hr  = acc[3][mt][nt][j] + bhr;
        float hz  = acc[4][mt][nt][j] + bhz;
        float hn  = acc[5][mt][nt][j] + bhn;
        float r  = 1.f / (1.f + __expf(-(ir + hr)));
        float z  = 1.f / (1.f + __expf(-(iz + hz)));
        float nn = tanhf(in_ + r * hn);
        size_t idx = (size_t)row * 128 + col;
        float hold = h[idx];
        float out  = (1.f - z) * nn + z * hold;
        h[idx]  = out;
        hb[idx] = __float2bfloat16(out);
      }
    }
  }
}

// ---------- per-node 1/max(||h||,eps) ----------
__global__ void k_norm(const float* __restrict__ h, float* __restrict__ rnorm, int n) {
  int node = (blockIdx.x * THREADS + threadIdx.x) >> 6;
  int lane = threadIdx.x & 63;
  if (node >= n) return;
  float2 v = ((const float2*)(h + (size_t)node * 128))[lane];
  float s = v.x * v.x + v.y * v.y;
#pragma unroll
  for (int d = 1; d < 64; d <<= 1) s += __shfl_xor(s, d);
  if (lane == 0) rnorm[node] = 1.f / fmaxf(sqrtf(s), 1e-12f);
}

// ---------- per-graph max/mean pool, split POOLS ways per graph ----------
__global__ void k_pool(const float* __restrict__ h, const float* __restrict__ rnorm,
                       const int* __restrict__ gs, const int* __restrict__ ge,
                       float* __restrict__ featp) {
  int g = blockIdx.x, sp = blockIdx.y;
  int c = threadIdx.x;  // 128
  int s = gs[g], e = ge[g];
  int len = e - s;
  int chunk = (len + POOLS - 1) / POOLS;
  int ns = s + sp * chunk;
  int ne = ns + chunk; if (ne > e) ne = e;
  float mx = 0.f, sm = 0.f;
  for (int nd = ns; nd < ne; ++nd) {
    float v = h[(size_t)nd * 128 + c] * rnorm[nd];
    v = fmaxf(v, 0.f);
    mx = fmaxf(mx, v);
    sm += v;
  }
  featp[((size_t)g * POOLS + sp) * 256 + c]       = mx;
  featp[((size_t)g * POOLS + sp) * 256 + 128 + c] = sm;
}

__global__ void k_pool2(const float* __restrict__ featp, const int* __restrict__ gs,
                        const int* __restrict__ ge, float* __restrict__ feat) {
  int g = blockIdx.x;
  int c = threadIdx.x;  // 256
  float mx = 0.f, sm = 0.f;
  for (int sp = 0; sp < POOLS; ++sp) {
    float v = featp[((size_t)g * POOLS + sp) * 256 + c];
    mx = fmaxf(mx, v);
    sm += v;
  }
  float cnt = fmaxf((float)(ge[g] - gs[g]), 1.f);
  feat[(size_t)g * 256 + c] = (c < 128) ? mx : (sm / cnt);
}

// ---------- final linear ----------
__global__ void k_final(const float* __restrict__ feat, const float* __restrict__ lin_w,
                        const float* __restrict__ lin_b, float* __restrict__ out) {
  int g = blockIdx.x;
  __shared__ float sf[256];
  sf[threadIdx.x] = feat[(size_t)g * 256 + threadIdx.x];
  __syncthreads();
  if (threadIdx.x < 10) {
    float s = lin_b[threadIdx.x];
    const float* w = lin_w + (size_t)threadIdx.x * 256;
#pragma unroll 8
    for (int c = 0; c < 256; ++c) s += sf[c] * w[c];
    out[(size_t)g * 10 + threadIdx.x] = s;
  }
}

extern "C" void kernel_launch(void* const* d_in, const int* in_sizes, int n_in,
                              void* d_out, int out_size, void* d_ws, size_t ws_size,
                              hipStream_t stream) {
  const float* x      = (const float*)d_in[0];
  const int*   ei     = (const int*)d_in[1];
  const int*   batch  = (const int*)d_in[2];
  const float* weight = (const float*)d_in[3];
  const float* w_ih   = (const float*)d_in[4];
  const float* w_hh   = (const float*)d_in[5];
  const float* b_ih   = (const float*)d_in[6];
  const float* b_hh   = (const float*)d_in[7];
  const float* lin_w  = (const float*)d_in[8];
  const float* lin_b  = (const float*)d_in[9];
  float* out = (float*)d_out;

  const int N = in_sizes[0] / 128;   // 100000
  const int E = in_sizes[1] / 2;     // 1600000
  const int G = out_size / 10;       // 64
  const int WP_PER_LAYER = 6 * 8 * 4 * 64 * 8;  // 98304

  char* wsc = (char*)d_ws;
  size_t off = 0;
  auto take = [&](size_t bytes) -> void* {
    void* p = wsc + off;
    off = align_up(off + bytes, 256);
    return p;
  };
  float*           h      = (float*)take((size_t)N * 128 * 4);
  __hip_bfloat16*  hb     = (__hip_bfloat16*)take((size_t)N * 128 * 2);
  __hip_bfloat16*  agg    = (__hip_bfloat16*)take((size_t)N * 128 * 2);
  float*           Wc     = (float*)take((size_t)3 * 384 * 128 * 4);
  __hip_bfloat16*  Wp     = (__hip_bfloat16*)take((size_t)3 * WP_PER_LAYER * 2);
  float*           rnorm  = (float*)take((size_t)N * 4);
  int*             counts = (int*)take((size_t)N * 4);
  int*             offs   = (int*)take(((size_t)N + 1) * 4);
  int*             cursor = (int*)take((size_t)N * 4);
  int*             bsum   = (int*)take(512 * 4);
  int*             csr    = (int*)take((size_t)E * 4);
  int*             gs     = (int*)take((size_t)G * 4);
  int*             ge     = (int*)take((size_t)G * 4);
  float*           featp  = (float*)take((size_t)G * POOLS * 256 * 4);
  float*           feat   = (float*)take((size_t)G * 256 * 4);
  int*             flag   = (int*)take(256);
  (void)ws_size; (void)n_in;

  hipMemsetAsync(counts, 0, (size_t)N * 4, stream);
  hipMemsetAsync(gs, 0, (size_t)G * 4, stream);
  hipMemsetAsync(ge, 0, (size_t)G * 4, stream);

  k_detect<<<1, 64, 0, stream>>>(ei, flag);
  k_wc<<<(3 * 384 * 128 + THREADS - 1) / THREADS, THREADS, 0, stream>>>(weight, w_ih, Wc);
  k_wprep<<<(3 * WP_PER_LAYER + THREADS - 1) / THREADS, THREADS, 0, stream>>>(Wc, w_hh, Wp);
  k_init<<<(N * 32 + THREADS - 1) / THREADS, THREADS, 0, stream>>>(x, h, hb, N * 32);

  int nb = (N + 255) / 256;
  k_hist<<<(E + THREADS - 1) / THREADS, THREADS, 0, stream>>>(ei, counts, E, flag);
  k_scan1<<<nb, 256, 0, stream>>>(counts, offs, bsum, N);
  k_scan2<<<1, 512, 0, stream>>>(bsum, nb);
  k_scan3<<<nb, 256, 0, stream>>>(offs, cursor, bsum, N, E);
  k_fill<<<(E + THREADS - 1) / THREADS, THREADS, 0, stream>>>(ei, cursor, csr, E, flag);
  k_bounds<<<nb, 256, 0, stream>>>(batch, gs, ge, N, flag);

  for (int layer = 0; layer < 3; ++layer) {
    k_agg<<<(N + 3) / 4, THREADS, 0, stream>>>(hb, offs, csr, agg, N);
    k_gru_mfma<<<(N + 31) / 32, 256, 0, stream>>>(
        agg, h, hb, Wp + (size_t)layer * WP_PER_LAYER, b_ih, b_hh, N);
  }

  k_norm<<<(N + 3) / 4, THREADS, 0, stream>>>(h, rnorm, N);
  k_pool<<<dim3(G, POOLS), 128, 0, stream>>>(h, rnorm, gs, ge, featp);
  k_pool2<<<G, 256, 0, stream>>>(featp, gs, ge, feat);
  k_final<<<G, 256, 0, stream>>>(feat, lin_w, lin_b, out);
}

// Round 3
// 755.573 us; speedup vs baseline: 3.4291x; 1.3729x over previous
//
#include <hip/hip_runtime.h>
#include <hip/hip_bf16.h>

#define THREADS 256
#define POOLS 16

typedef __attribute__((ext_vector_type(8))) short bf16x8;
typedef __attribute__((ext_vector_type(4))) float f32x4;

static inline size_t align_up(size_t x, size_t a) { return (x + a - 1) & ~(a - 1); }

__device__ __forceinline__ float bf_lo(unsigned v) { return __uint_as_float(v << 16); }
__device__ __forceinline__ float bf_hi(unsigned v) { return __uint_as_float(v & 0xffff0000u); }

// ---------- detect whether index inputs are stored as int64 (low/high words) ----------
__global__ void k_detect(const int* __restrict__ ei, int* __restrict__ flag) {
  if (blockIdx.x == 0 && threadIdx.x == 0) {
    int odd_zero = ((ei[1] | ei[3] | ei[5] | ei[7]) == 0);
    int even_nz  = ((ei[0] | ei[2] | ei[4] | ei[6]) != 0);
    flag[0] = (odd_zero && even_nz) ? 1 : 0;
  }
}

// ---------- Wc[i][j][k] = sum_t weight[i][k][t] * w_ih[j][t]  (3 x 384 x 128) ----------
__global__ void k_wc(const float* __restrict__ weight, const float* __restrict__ w_ih,
                     float* __restrict__ Wc) {
  int idx = blockIdx.x * blockDim.x + threadIdx.x;
  const int total = 3 * 384 * 128;
  if (idx >= total) return;
  int k = idx & 127;
  int j = (idx >> 7) % 384;
  int i = idx / (384 * 128);
  const float* wp = weight + (size_t)i * (128 * 128) + (size_t)k * 128;
  const float* ip = w_ih + (size_t)j * 128;
  float s = 0.f;
#pragma unroll 8
  for (int t = 0; t < 128; ++t) s += wp[t] * ip[t];
  Wc[idx] = s;
}

// ---------- pack weights into MFMA fragment-major bf16 layout ----------
// Wp[layer][g(6)][ct(8)][ks(4)][lane(64)][j(8)]
//   row = (g%3)*128 + ct*16 + (lane&15);  k = ks*32 + (lane>>4)*8 + j
__global__ void k_wprep(const float* __restrict__ Wc, const float* __restrict__ whh,
                        __hip_bfloat16* __restrict__ Wp) {
  int idx = blockIdx.x * blockDim.x + threadIdx.x;
  const int per_layer = 6 * 8 * 4 * 64 * 8;  // 98304
  if (idx >= 3 * per_layer) return;
  int layer = idx / per_layer;
  int rem = idx % per_layer;
  int j    = rem & 7;
  int lane = (rem >> 3) & 63;
  int ks   = (rem >> 9) & 3;
  int ct   = (rem >> 11) & 7;
  int g    = rem >> 14;  // 0..5
  int row = (g % 3) * 128 + ct * 16 + (lane & 15);
  int k   = ks * 32 + (lane >> 4) * 8 + j;
  float v = (g < 3) ? Wc[(size_t)layer * 384 * 128 + (size_t)row * 128 + k]
                    : whh[(size_t)row * 128 + k];
  Wp[idx] = __float2bfloat16(v);
}

// ---------- hb = bf16(x) ----------
__global__ void k_init(const float* __restrict__ x, __hip_bfloat16* __restrict__ hb,
                       int total4) {
  int i = blockIdx.x * blockDim.x + threadIdx.x;
  if (i >= total4) return;
  float4 v = ((const float4*)x)[i];
  __hip_bfloat162 a, b;
  a.x = __float2bfloat16(v.x); a.y = __float2bfloat16(v.y);
  b.x = __float2bfloat16(v.z); b.y = __float2bfloat16(v.w);
  ((__hip_bfloat162*)hb)[2 * i]     = a;
  ((__hip_bfloat162*)hb)[2 * i + 1] = b;
}

// ---------- CSR build ----------
__global__ void k_hist(const int* __restrict__ ei, int* __restrict__ counts,
                       int E, const int* __restrict__ flag) {
  int i = blockIdx.x * blockDim.x + threadIdx.x;
  if (i >= E) return;
  int s64 = flag[0];
  size_t idx = s64 ? 2 * ((size_t)E + (size_t)i) : ((size_t)E + (size_t)i);
  atomicAdd(&counts[ei[idx]], 1);
}

__global__ void k_scan1(const int* __restrict__ counts, int* __restrict__ offs,
                        int* __restrict__ bsum, int n) {
  __shared__ int s[256];
  int b = blockIdx.x, t = threadIdx.x;
  int i = b * 256 + t;
  int v = (i < n) ? counts[i] : 0;
  s[t] = v;
  __syncthreads();
  for (int d = 1; d < 256; d <<= 1) {
    int x = (t >= d) ? s[t - d] : 0;
    __syncthreads();
    s[t] += x;
    __syncthreads();
  }
  if (i < n) offs[i] = s[t] - v;
  if (t == 255) bsum[b] = s[t];
}

__global__ void k_scan2(int* __restrict__ bsum, int nb) {
  __shared__ int s[512];
  int t = threadIdx.x;
  int v = (t < nb) ? bsum[t] : 0;
  s[t] = v;
  __syncthreads();
  for (int d = 1; d < 512; d <<= 1) {
    int x = (t >= d) ? s[t - d] : 0;
    __syncthreads();
    s[t] += x;
    __syncthreads();
  }
  if (t < nb) bsum[t] = s[t] - v;
}

__global__ void k_scan3(int* __restrict__ offs, int* __restrict__ cursor,
                        const int* __restrict__ bsum, int n, int total) {
  int i = blockIdx.x * blockDim.x + threadIdx.x;
  if (i < n) {
    int o = offs[i] + bsum[i >> 8];
    offs[i] = o;
    cursor[i] = o;
  }
  if (i == 0) offs[n] = total;
}

__global__ void k_fill(const int* __restrict__ ei, int* __restrict__ cursor,
                       int* __restrict__ csr, int E, const int* __restrict__ flag) {
  int i = blockIdx.x * blockDim.x + threadIdx.x;
  if (i >= E) return;
  int s64 = flag[0];
  int sv = ei[s64 ? 2 * (size_t)i : (size_t)i];
  int dv = ei[s64 ? 2 * ((size_t)E + (size_t)i) : ((size_t)E + (size_t)i)];
  int pos = atomicAdd(&cursor[dv], 1);
  csr[pos] = sv;
}

__global__ void k_bounds(const int* __restrict__ batch, int* __restrict__ gs,
                         int* __restrict__ ge, int n, const int* __restrict__ flag) {
  int i = blockIdx.x * blockDim.x + threadIdx.x;
  if (i >= n) return;
  int s64 = flag[0];
  int b  = batch[s64 ? 2 * (size_t)i : (size_t)i];
  int bp = (i > 0)     ? batch[s64 ? 2 * (size_t)(i - 1) : (size_t)(i - 1)] : -1;
  int bn = (i < n - 1) ? batch[s64 ? 2 * (size_t)(i + 1) : (size_t)(i + 1)] : -1;
  if (i == 0 || bp != b) gs[b] = i;
  if (i == n - 1 || bn != b) ge[b] = i + 1;
}

// ---------- aggregation: agg[n] = sum over in-edges of hb[src]; deep-MLP gather ----------
__global__ void k_agg(const __hip_bfloat16* __restrict__ hb, const int* __restrict__ offs,
                      const int* __restrict__ csr, __hip_bfloat16* __restrict__ agg, int n) {
  int node = (blockIdx.x * THREADS + threadIdx.x) >> 6;
  int lane = threadIdx.x & 63;
  if (node >= n) return;
  const unsigned* base = (const unsigned*)hb + lane;  // row stride = 64 uints
  int s = offs[node], e = offs[node + 1];
  float ax0 = 0.f, ay0 = 0.f, ax1 = 0.f, ay1 = 0.f;
  float ax2 = 0.f, ay2 = 0.f, ax3 = 0.f, ay3 = 0.f;
  for (int bs = s; bs < e; bs += 64) {
    int cnt = e - bs; if (cnt > 64) cnt = 64;
    int idx = csr[bs + ((lane < cnt) ? lane : (cnt - 1))];  // one coalesced load
    int j = 0;
    for (; j + 8 <= cnt; j += 8) {
      int s0 = __shfl(idx, j + 0), s1 = __shfl(idx, j + 1);
      int s2 = __shfl(idx, j + 2), s3 = __shfl(idx, j + 3);
      int s4 = __shfl(idx, j + 4), s5 = __shfl(idx, j + 5);
      int s6 = __shfl(idx, j + 6), s7 = __shfl(idx, j + 7);
      unsigned v0 = base[(size_t)s0 * 64], v1 = base[(size_t)s1 * 64];
      unsigned v2 = base[(size_t)s2 * 64], v3 = base[(size_t)s3 * 64];
      unsigned v4 = base[(size_t)s4 * 64], v5 = base[(size_t)s5 * 64];
      unsigned v6 = base[(size_t)s6 * 64], v7 = base[(size_t)s7 * 64];
      ax0 += bf_lo(v0); ay0 += bf_hi(v0); ax1 += bf_lo(v1); ay1 += bf_hi(v1);
      ax2 += bf_lo(v2); ay2 += bf_hi(v2); ax3 += bf_lo(v3); ay3 += bf_hi(v3);
      ax0 += bf_lo(v4); ay0 += bf_hi(v4); ax1 += bf_lo(v5); ay1 += bf_hi(v5);
      ax2 += bf_lo(v6); ay2 += bf_hi(v6); ax3 += bf_lo(v7); ay3 += bf_hi(v7);
    }
    for (; j < cnt; ++j) {
      unsigned v = base[(size_t)__shfl(idx, j) * 64];
      ax0 += bf_lo(v); ay0 += bf_hi(v);
    }
  }
  float ax = (ax0 + ax1) + (ax2 + ax3);
  float ay = (ay0 + ay1) + (ay2 + ay3);
  __hip_bfloat162 o;
  o.x = __float2bfloat16(ax);
  o.y = __float2bfloat16(ay);
  *(__hip_bfloat162*)(agg + (size_t)node * 128 + lane * 2) = o;
}

// ---------- fused MFMA GRU: hb = GRUCell(agg, hb) in place (bf16 state) ----------
// block: 256 threads = 4 waves; 32 rows x 128 cols; wave wc owns cols [wc*32, wc*32+32)
// LAST: also computes rnorm[row] = 1/max(||h_row||,eps) from f32 registers
template <bool LAST>
__launch_bounds__(256, 2)
__global__ void k_gru_mfma(const __hip_bfloat16* __restrict__ agg,
                           __hip_bfloat16* __restrict__ hb,
                           const __hip_bfloat16* __restrict__ Wp,  // layer slice, frag-major
                           const float* __restrict__ b_ih,
                           const float* __restrict__ b_hh,
                           float* __restrict__ rnorm,
                           int n) {
  __shared__ __align__(16) __hip_bfloat16 sA[2][32][128];  // [agg|h][row][k] chunk-swizzled
  __shared__ float ssq[32];
  const int t = threadIdx.x;
  const int lane = t & 63;
  const int wc = t >> 6;
  const int row0 = blockIdx.x * 32;

  if (LAST && t < 32) ssq[t] = 0.f;

  // stage A: 2 matrices x 32 rows x 16 chunks(16B); chunk-XOR swizzle vs bank conflicts
  for (int i = t; i < 2 * 32 * 16; i += 256) {
    int m   = i >> 9;
    int row = (i >> 4) & 31;
    int c   = i & 15;
    int gr  = row0 + row;
    uint4 v = make_uint4(0u, 0u, 0u, 0u);
    const __hip_bfloat16* src = m ? hb : agg;
    if (gr < n) v = *(const uint4*)(src + (size_t)gr * 128 + c * 8);
    *(uint4*)(&sA[m][row][(c ^ (row & 7)) * 8]) = v;
  }
  __syncthreads();

  f32x4 acc[6][2][2];
#pragma unroll
  for (int g = 0; g < 6; ++g)
#pragma unroll
    for (int mt = 0; mt < 2; ++mt)
#pragma unroll
      for (int nt = 0; nt < 2; ++nt)
        acc[g][mt][nt] = (f32x4){0.f, 0.f, 0.f, 0.f};

  const int nrow = lane & 15;
  const int kgrp = lane >> 4;

  for (int ks = 0; ks < 4; ++ks) {
    bf16x8 af[2][2];
#pragma unroll
    for (int m = 0; m < 2; ++m)
#pragma unroll
      for (int mt = 0; mt < 2; ++mt) {
        int row = mt * 16 + nrow;
        int kc  = ks * 4 + kgrp;
        af[m][mt] = *(const bf16x8*)(&sA[m][row][(kc ^ (row & 7)) * 8]);
      }
    bf16x8 bfr[6][2];
#pragma unroll
    for (int g = 0; g < 6; ++g)
#pragma unroll
      for (int nt = 0; nt < 2; ++nt) {
        size_t boff = ((((size_t)g * 8 + (wc * 2 + nt)) * 4 + (size_t)ks) * 64 + lane) * 8;
        bfr[g][nt] = *(const bf16x8*)(Wp + boff);
      }
#pragma unroll
    for (int g = 0; g < 6; ++g)
#pragma unroll
      for (int mt = 0; mt < 2; ++mt)
#pragma unroll
        for (int nt = 0; nt < 2; ++nt)
          acc[g][mt][nt] = __builtin_amdgcn_mfma_f32_16x16x32_bf16(
              af[g < 3 ? 0 : 1][mt], bfr[g][nt], acc[g][mt][nt], 0, 0, 0);
  }

  // epilogue: gates -> hb (bf16 state); h_old read from staged LDS tile
#pragma unroll
  for (int nt = 0; nt < 2; ++nt) {
    int col = wc * 32 + nt * 16 + nrow;
    float bir = b_ih[col], biz = b_ih[128 + col], bin = b_ih[256 + col];
    float bhr = b_hh[col], bhz = b_hh[128 + col], bhn = b_hh[256 + col];
    int swc = col >> 3, sel = col & 7;
#pragma unroll
    for (int mt = 0; mt < 2; ++mt) {
#pragma unroll
      for (int j = 0; j < 4; ++j) {
        int lr = mt * 16 + kgrp * 4 + j;
        int row = row0 + lr;
        if (row >= n) continue;
        float ir  = acc[0][mt][nt][j] + bir;
        float iz  = acc[1][mt][nt][j] + biz;
        float in_ = acc[2][mt][nt][j] + bin;
        float hr  = acc[3][mt][nt][j] + bhr;
        float hz  = acc[4][mt][nt][j] + bhz;
        float hn  = acc[5][mt][nt][j] + bhn;
        float r  = 1.f / (1.f + __expf(-(ir + hr)));
        float z  = 1.f / (1.f + __expf(-(iz + hz)));
        float nn = tanhf(in_ + r * hn);
        float hold = __bfloat162float(sA[1][lr][(swc ^ (lr & 7)) * 8 + sel]);
        float out  = (1.f - z) * nn + z * hold;
        hb[(size_t)row * 128 + col] = __float2bfloat16(out);
        if (LAST) atomicAdd(&ssq[lr], out * out);
      }
    }
  }

  if (LAST) {
    __syncthreads();
    if (t < 32) {
      int row = row0 + t;
      if (row < n) rnorm[row] = 1.f / fmaxf(sqrtf(ssq[t]), 1e-12f);
    }
  }
}

// ---------- per-graph max/mean pool of relu(hb * rnorm), split POOLS ways ----------
__global__ void k_pool(const __hip_bfloat16* __restrict__ hb, const float* __restrict__ rnorm,
                       const int* __restrict__ gs, const int* __restrict__ ge,
                       float* __restrict__ featp) {
  int g = blockIdx.x, sp = blockIdx.y;
  int c = threadIdx.x;  // 128
  int s = gs[g], e = ge[g];
  int len = e - s;
  int chunk = (len + POOLS - 1) / POOLS;
  int ns = s + sp * chunk;
  int ne = ns + chunk; if (ne > e) ne = e;
  float mx = 0.f, sm = 0.f;
  for (int nd = ns; nd < ne; ++nd) {
    float v = __bfloat162float(hb[(size_t)nd * 128 + c]) * rnorm[nd];
    v = fmaxf(v, 0.f);
    mx = fmaxf(mx, v);
    sm += v;
  }
  featp[((size_t)g * POOLS + sp) * 256 + c]       = mx;
  featp[((size_t)g * POOLS + sp) * 256 + 128 + c] = sm;
}

__global__ void k_pool2(const float* __restrict__ featp, const int* __restrict__ gs,
                        const int* __restrict__ ge, float* __restrict__ feat) {
  int g = blockIdx.x;
  int c = threadIdx.x;  // 256
  float mx = 0.f, sm = 0.f;
  for (int sp = 0; sp < POOLS; ++sp) {
    float v = featp[((size_t)g * POOLS + sp) * 256 + c];
    mx = fmaxf(mx, v);
    sm += v;
  }
  float cnt = fmaxf((float)(ge[g] - gs[g]), 1.f);
  feat[(size_t)g * 256 + c] = (c < 128) ? mx : (sm / cnt);
}

// ---------- final linear ----------
__global__ void k_final(const float* __restrict__ feat, const float* __restrict__ lin_w,
                        const float* __restrict__ lin_b, float* __restrict__ out) {
  int g = blockIdx.x;
  __shared__ float sf[256];
  sf[threadIdx.x] = feat[(size_t)g * 256 + threadIdx.x];
  __syncthreads();
  if (threadIdx.x < 10) {
    float s = lin_b[threadIdx.x];
    const float* w = lin_w + (size_t)threadIdx.x * 256;
#pragma unroll 8
    for (int c = 0; c < 256; ++c) s += sf[c] * w[c];
    out[(size_t)g * 10 + threadIdx.x] = s;
  }
}

extern "C" void kernel_launch(void* const* d_in, const int* in_sizes, int n_in,
                              void* d_out, int out_size, void* d_ws, size_t ws_size,
                              hipStream_t stream) {
  const float* x      = (const float*)d_in[0];
  const int*   ei     = (const int*)d_in[1];
  const int*   batch  = (const int*)d_in[2];
  const float* weight = (const float*)d_in[3];
  const float* w_ih   = (const float*)d_in[4];
  const float* w_hh   = (const float*)d_in[5];
  const float* b_ih   = (const float*)d_in[6];
  const float* b_hh   = (const float*)d_in[7];
  const float* lin_w  = (const float*)d_in[8];
  const float* lin_b  = (const float*)d_in[9];
  float* out = (float*)d_out;

  const int N = in_sizes[0] / 128;   // 100000
  const int E = in_sizes[1] / 2;     // 1600000
  const int G = out_size / 10;       // 64
  const int WP_PER_LAYER = 6 * 8 * 4 * 64 * 8;  // 98304

  char* wsc = (char*)d_ws;
  size_t off = 0;
  auto take = [&](size_t bytes) -> void* {
    void* p = wsc + off;
    off = align_up(off + bytes, 256);
    return p;
  };
  __hip_bfloat16*  hb     = (__hip_bfloat16*)take((size_t)N * 128 * 2);
  __hip_bfloat16*  agg    = (__hip_bfloat16*)take((size_t)N * 128 * 2);
  float*           Wc     = (float*)take((size_t)3 * 384 * 128 * 4);
  __hip_bfloat16*  Wp     = (__hip_bfloat16*)take((size_t)3 * WP_PER_LAYER * 2);
  float*           rnorm  = (float*)take((size_t)N * 4);
  int*             counts = (int*)take((size_t)N * 4);
  int*             offs   = (int*)take(((size_t)N + 1) * 4);
  int*             cursor = (int*)take((size_t)N * 4);
  int*             bsum   = (int*)take(512 * 4);
  int*             csr    = (int*)take((size_t)E * 4);
  int*             gs     = (int*)take((size_t)G * 4);
  int*             ge     = (int*)take((size_t)G * 4);
  float*           featp  = (float*)take((size_t)G * POOLS * 256 * 4);
  float*           feat   = (float*)take((size_t)G * 256 * 4);
  int*             flag   = (int*)take(256);
  (void)ws_size; (void)n_in;

  hipMemsetAsync(counts, 0, (size_t)N * 4, stream);
  hipMemsetAsync(gs, 0, (size_t)G * 4, stream);
  hipMemsetAsync(ge, 0, (size_t)G * 4, stream);

  k_detect<<<1, 64, 0, stream>>>(ei, flag);
  k_wc<<<(3 * 384 * 128 + THREADS - 1) / THREADS, THREADS, 0, stream>>>(weight, w_ih, Wc);
  k_wprep<<<(3 * WP_PER_LAYER + THREADS - 1) / THREADS, THREADS, 0, stream>>>(Wc, w_hh, Wp);
  k_init<<<(N * 32 + THREADS - 1) / THREADS, THREADS, 0, stream>>>(x, hb, N * 32);

  int nb = (N + 255) / 256;
  k_hist<<<(E + THREADS - 1) / THREADS, THREADS, 0, stream>>>(ei, counts, E, flag);
  k_scan1<<<nb, 256, 0, stream>>>(counts, offs, bsum, N);
  k_scan2<<<1, 512, 0, stream>>>(bsum, nb);
  k_scan3<<<nb, 256, 0, stream>>>(offs, cursor, bsum, N, E);
  k_fill<<<(E + THREADS - 1) / THREADS, THREADS, 0, stream>>>(ei, cursor, csr, E, flag);
  k_bounds<<<nb, 256, 0, stream>>>(batch, gs, ge, N, flag);

  for (int layer = 0; layer < 3; ++layer) {
    k_agg<<<(N + 3) / 4, THREADS, 0, stream>>>(hb, offs, csr, agg, N);
    if (layer < 2)
      k_gru_mfma<false><<<(N + 31) / 32, 256, 0, stream>>>(
          agg, hb, Wp + (size_t)layer * WP_PER_LAYER, b_ih, b_hh, rnorm, N);
    else
      k_gru_mfma<true><<<(N + 31) / 32, 256, 0, stream>>>(
          agg, hb, Wp + (size_t)layer * WP_PER_LAYER, b_ih, b_hh, rnorm, N);
  }

  k_pool<<<dim3(G, POOLS), 128, 0, stream>>>(hb, rnorm, gs, ge, featp);
  k_pool2<<<G, 256, 0, stream>>>(featp, gs, ge, feat);
  k_final<<<G, 256, 0, stream>>>(feat, lin_w, lin_b, out);
}

// Round 4
// 599.609 us; speedup vs baseline: 4.3210x; 1.2601x over previous
//
#include <hip/hip_runtime.h>
#include <hip/hip_bf16.h>

#define THREADS 256
#define POOLS 16

typedef __attribute__((ext_vector_type(8))) short bf16x8;
typedef __attribute__((ext_vector_type(4))) float f32x4;

static inline size_t align_up(size_t x, size_t a) { return (x + a - 1) & ~(a - 1); }

__device__ __forceinline__ float bf_lo(unsigned v) { return __uint_as_float(v << 16); }
__device__ __forceinline__ float bf_hi(unsigned v) { return __uint_as_float(v & 0xffff0000u); }

__device__ __forceinline__ void gl_lds16(const void* g, void* l) {
  __builtin_amdgcn_global_load_lds(
      (const __attribute__((address_space(1))) unsigned*)g,
      (__attribute__((address_space(3))) unsigned*)l, 16, 0, 0);
}

// ---------- detect whether index inputs are stored as int64 (low/high words) ----------
__global__ void k_detect(const int* __restrict__ ei, int* __restrict__ flag) {
  if (blockIdx.x == 0 && threadIdx.x == 0) {
    int odd_zero = ((ei[1] | ei[3] | ei[5] | ei[7]) == 0);
    int even_nz  = ((ei[0] | ei[2] | ei[4] | ei[6]) != 0);
    flag[0] = (odd_zero && even_nz) ? 1 : 0;
  }
}

// ---------- Wc[i][j][k] = sum_t weight[i][k][t] * w_ih[j][t]  (3 x 384 x 128) ----------
__global__ void k_wc(const float* __restrict__ weight, const float* __restrict__ w_ih,
                     float* __restrict__ Wc) {
  int idx = blockIdx.x * blockDim.x + threadIdx.x;
  const int total = 3 * 384 * 128;
  if (idx >= total) return;
  int k = idx & 127;
  int j = (idx >> 7) % 384;
  int i = idx / (384 * 128);
  const float* wp = weight + (size_t)i * (128 * 128) + (size_t)k * 128;
  const float* ip = w_ih + (size_t)j * 128;
  float s = 0.f;
#pragma unroll 8
  for (int t = 0; t < 128; ++t) s += wp[t] * ip[t];
  Wc[idx] = s;
}

// ---------- pack weights: Wp[layer][wc(8)][f(24)][lane(64)][j(8)] bf16 ----------
// f 0-7: r (ks=f; ks<4 -> Wc_r, ks>=4 -> Whh_r); f 8-15: z; f 16-19: i_n (Wc_n);
// f 20-23: h_n (Whh_n).  col = wc*16+(lane&15), k_local = (lane>>4)*8+j.
__global__ void k_wprep(const float* __restrict__ Wc, const float* __restrict__ whh,
                        __hip_bfloat16* __restrict__ Wp) {
  int idx = blockIdx.x * blockDim.x + threadIdx.x;
  const int per_layer = 8 * 24 * 64 * 8;  // 98304
  if (idx >= 3 * per_layer) return;
  int layer = idx / per_layer;
  int rem = idx % per_layer;
  int j    = rem & 7;
  int lane = (rem >> 3) & 63;
  int f    = (rem >> 9) % 24;
  int wc   = rem / (24 * 512);
  int col  = wc * 16 + (lane & 15);
  int kl   = (lane >> 4) * 8 + j;
  float v;
  const float* wcl = Wc + (size_t)layer * 384 * 128;
  if (f < 8) {
    int ks = f;
    v = (ks < 4) ? wcl[(size_t)col * 128 + ks * 32 + kl]
                 : whh[(size_t)col * 128 + (ks - 4) * 32 + kl];
  } else if (f < 16) {
    int ks = f - 8;
    v = (ks < 4) ? wcl[(size_t)(128 + col) * 128 + ks * 32 + kl]
                 : whh[(size_t)(128 + col) * 128 + (ks - 4) * 32 + kl];
  } else if (f < 20) {
    int ks = f - 16;
    v = wcl[(size_t)(256 + col) * 128 + ks * 32 + kl];
  } else {
    int ks = f - 20;
    v = whh[(size_t)(256 + col) * 128 + ks * 32 + kl];
  }
  Wp[idx] = __float2bfloat16(v);
}

// ---------- hb = bf16(x) ----------
__global__ void k_init(const float* __restrict__ x, __hip_bfloat16* __restrict__ hb,
                       int total4) {
  int i = blockIdx.x * blockDim.x + threadIdx.x;
  if (i >= total4) return;
  float4 v = ((const float4*)x)[i];
  __hip_bfloat162 a, b;
  a.x = __float2bfloat16(v.x); a.y = __float2bfloat16(v.y);
  b.x = __float2bfloat16(v.z); b.y = __float2bfloat16(v.w);
  ((__hip_bfloat162*)hb)[2 * i]     = a;
  ((__hip_bfloat162*)hb)[2 * i + 1] = b;
}

// ---------- CSR build ----------
__global__ void k_hist(const int* __restrict__ ei, int* __restrict__ counts,
                       int E, const int* __restrict__ flag) {
  int i = blockIdx.x * blockDim.x + threadIdx.x;
  if (i >= E) return;
  int s64 = flag[0];
  size_t idx = s64 ? 2 * ((size_t)E + (size_t)i) : ((size_t)E + (size_t)i);
  atomicAdd(&counts[ei[idx]], 1);
}

__global__ void k_scan1(const int* __restrict__ counts, int* __restrict__ offs,
                        int* __restrict__ bsum, int n) {
  __shared__ int s[256];
  int b = blockIdx.x, t = threadIdx.x;
  int i = b * 256 + t;
  int v = (i < n) ? counts[i] : 0;
  s[t] = v;
  __syncthreads();
  for (int d = 1; d < 256; d <<= 1) {
    int x = (t >= d) ? s[t - d] : 0;
    __syncthreads();
    s[t] += x;
    __syncthreads();
  }
  if (i < n) offs[i] = s[t] - v;
  if (t == 255) bsum[b] = s[t];
}

__global__ void k_scan2(int* __restrict__ bsum, int nb) {
  __shared__ int s[512];
  int t = threadIdx.x;
  int v = (t < nb) ? bsum[t] : 0;
  s[t] = v;
  __syncthreads();
  for (int d = 1; d < 512; d <<= 1) {
    int x = (t >= d) ? s[t - d] : 0;
    __syncthreads();
    s[t] += x;
    __syncthreads();
  }
  if (t < nb) bsum[t] = s[t] - v;
}

__global__ void k_scan3(int* __restrict__ offs, int* __restrict__ cursor,
                        const int* __restrict__ bsum, int n, int total) {
  int i = blockIdx.x * blockDim.x + threadIdx.x;
  if (i < n) {
    int o = offs[i] + bsum[i >> 8];
    offs[i] = o;
    cursor[i] = o;
  }
  if (i == 0) offs[n] = total;
}

__global__ void k_fill(const int* __restrict__ ei, int* __restrict__ cursor,
                       int* __restrict__ csr, int E, const int* __restrict__ flag) {
  int i = blockIdx.x * blockDim.x + threadIdx.x;
  if (i >= E) return;
  int s64 = flag[0];
  int sv = ei[s64 ? 2 * (size_t)i : (size_t)i];
  int dv = ei[s64 ? 2 * ((size_t)E + (size_t)i) : ((size_t)E + (size_t)i)];
  int pos = atomicAdd(&cursor[dv], 1);
  csr[pos] = sv;
}

__global__ void k_bounds(const int* __restrict__ batch, int* __restrict__ gs,
                         int* __restrict__ ge, int n, const int* __restrict__ flag) {
  int i = blockIdx.x * blockDim.x + threadIdx.x;
  if (i >= n) return;
  int s64 = flag[0];
  int b  = batch[s64 ? 2 * (size_t)i : (size_t)i];
  int bp = (i > 0)     ? batch[s64 ? 2 * (size_t)(i - 1) : (size_t)(i - 1)] : -1;
  int bn = (i < n - 1) ? batch[s64 ? 2 * (size_t)(i + 1) : (size_t)(i + 1)] : -1;
  if (i == 0 || bp != b) gs[b] = i;
  if (i == n - 1 || bn != b) ge[b] = i + 1;
}

// ---------- aggregation: agg[n] = sum over in-edges of hb[src]; deep-MLP gather ----------
__global__ void k_agg(const __hip_bfloat16* __restrict__ hb, const int* __restrict__ offs,
                      const int* __restrict__ csr, __hip_bfloat16* __restrict__ agg, int n) {
  int node = (blockIdx.x * THREADS + threadIdx.x) >> 6;
  int lane = threadIdx.x & 63;
  if (node >= n) return;
  const unsigned* base = (const unsigned*)hb + lane;  // row stride = 64 uints
  int s = offs[node], e = offs[node + 1];
  float ax0 = 0.f, ay0 = 0.f, ax1 = 0.f, ay1 = 0.f;
  float ax2 = 0.f, ay2 = 0.f, ax3 = 0.f, ay3 = 0.f;
  for (int bs = s; bs < e; bs += 64) {
    int cnt = e - bs; if (cnt > 64) cnt = 64;
    int idx = csr[bs + ((lane < cnt) ? lane : (cnt - 1))];  // one coalesced load
    int j = 0;
    for (; j + 8 <= cnt; j += 8) {
      int s0 = __shfl(idx, j + 0), s1 = __shfl(idx, j + 1);
      int s2 = __shfl(idx, j + 2), s3 = __shfl(idx, j + 3);
      int s4 = __shfl(idx, j + 4), s5 = __shfl(idx, j + 5);
      int s6 = __shfl(idx, j + 6), s7 = __shfl(idx, j + 7);
      unsigned v0 = base[(size_t)s0 * 64], v1 = base[(size_t)s1 * 64];
      unsigned v2 = base[(size_t)s2 * 64], v3 = base[(size_t)s3 * 64];
      unsigned v4 = base[(size_t)s4 * 64], v5 = base[(size_t)s5 * 64];
      unsigned v6 = base[(size_t)s6 * 64], v7 = base[(size_t)s7 * 64];
      ax0 += bf_lo(v0); ay0 += bf_hi(v0); ax1 += bf_lo(v1); ay1 += bf_hi(v1);
      ax2 += bf_lo(v2); ay2 += bf_hi(v2); ax3 += bf_lo(v3); ay3 += bf_hi(v3);
      ax0 += bf_lo(v4); ay0 += bf_hi(v4); ax1 += bf_lo(v5); ay1 += bf_hi(v5);
      ax2 += bf_lo(v6); ay2 += bf_hi(v6); ax3 += bf_lo(v7); ay3 += bf_hi(v7);
    }
    for (; j < cnt; ++j) {
      unsigned v = base[(size_t)__shfl(idx, j) * 64];
      ax0 += bf_lo(v); ay0 += bf_hi(v);
    }
  }
  float ax = (ax0 + ax1) + (ax2 + ax3);
  float ay = (ay0 + ay1) + (ay2 + ay3);
  __hip_bfloat162 o;
  o.x = __float2bfloat16(ax);
  o.y = __float2bfloat16(ay);
  *(__hip_bfloat162*)(agg + (size_t)node * 128 + lane * 2) = o;
}

// ---------- persistent MFMA GRU: hb = GRUCell(agg, hb) in place ----------
// 512 threads = 8 waves; wave wc owns output cols [wc*16, wc*16+16), all 4 gates.
// Weights register-resident (24 bf16x8/lane, loaded once). Blocks loop over
// 32-row tiles (stride gridDim), double-buffered LDS A-staging via
// global_load_lds with pre-swizzled source (XOR-chunk swizzle).
__launch_bounds__(512, 2)
__global__ void k_gru_pers(const __hip_bfloat16* __restrict__ agg,
                           __hip_bfloat16* __restrict__ hb,
                           const __hip_bfloat16* __restrict__ Wp,  // layer slice
                           const float* __restrict__ b_ih,
                           const float* __restrict__ b_hh,
                           int n, int ntiles) {
  __shared__ __align__(16) __hip_bfloat16 sA[2][2][32 * 128];  // [dbuf][agg|h]
  const int t    = threadIdx.x;
  const int lane = t & 63;
  const int wc   = t >> 6;            // wave id 0..7 = col-tile

  // ---- weights -> registers (once) ----
  bf16x8 w[24];
  {
    const bf16x8* wp = (const bf16x8*)Wp + (size_t)(wc * 24) * 64 + lane;
#pragma unroll
    for (int f = 0; f < 24; ++f) w[f] = wp[(size_t)f * 64];
  }
  // ---- per-lane biases ----
  const int col = wc * 16 + (lane & 15);
  const float br  = b_ih[col] + b_hh[col];
  const float bz  = b_ih[128 + col] + b_hh[128 + col];
  const float bin = b_ih[256 + col];
  const float bhn = b_hh[256 + col];

  // staging source addressing (pre-swizzled so linear LDS dest ends up swizzled)
  const int srow = t >> 4;                 // 0..31
  const int ssc  = (t & 15) ^ (srow & 7);  // source chunk
  const int soff = srow * 256 + ssc * 16;  // byte offset within a tile

  auto stage = [&](int buf, int tileIdx) {
    const char* ga = (const char*)(agg + (size_t)tileIdx * 32 * 128) + soff;
    const char* gh = (const char*)(hb  + (size_t)tileIdx * 32 * 128) + soff;
    char* la = (char*)&sA[buf][0][0] + wc * 1024;   // wave-uniform LDS base
    char* lh = (char*)&sA[buf][1][0] + wc * 1024;
    gl_lds16(ga, la);
    gl_lds16(gh, lh);
  };

  const int nblk = gridDim.x;
  int tile = blockIdx.x;
  if (tile < ntiles) stage(0, tile);
  int cur = 0;

  for (; tile < ntiles; tile += nblk) {
    __syncthreads();   // drains vmem: buf[cur] ready; prev iter's reads done
    int nxt = tile + nblk;
    if (nxt < ntiles) stage(cur ^ 1, nxt);

    const char* cb = (const char*)&sA[cur][0][0];
    f32x4 ar[2], az[2], ain[2], ahn[2];
#pragma unroll
    for (int mt = 0; mt < 2; ++mt) {
      ar[mt] = (f32x4){0.f, 0.f, 0.f, 0.f};
      az[mt] = (f32x4){0.f, 0.f, 0.f, 0.f};
      ain[mt] = (f32x4){0.f, 0.f, 0.f, 0.f};
      ahn[mt] = (f32x4){0.f, 0.f, 0.f, 0.f};
    }

#pragma unroll
    for (int ks = 0; ks < 4; ++ks) {
      bf16x8 aa[2], ah[2];
#pragma unroll
      for (int mt = 0; mt < 2; ++mt) {
        int row = mt * 16 + (lane & 15);
        int ch  = (ks * 4 + (lane >> 4)) ^ (row & 7);
        aa[mt] = *(const bf16x8*)(cb + row * 256 + ch * 16);
        ah[mt] = *(const bf16x8*)(cb + 8192 + row * 256 + ch * 16);
      }
#pragma unroll
      for (int mt = 0; mt < 2; ++mt) {
        ar[mt]  = __builtin_amdgcn_mfma_f32_16x16x32_bf16(aa[mt], w[ks],      ar[mt], 0, 0, 0);
        ar[mt]  = __builtin_amdgcn_mfma_f32_16x16x32_bf16(ah[mt], w[4 + ks],  ar[mt], 0, 0, 0);
        az[mt]  = __builtin_amdgcn_mfma_f32_16x16x32_bf16(aa[mt], w[8 + ks],  az[mt], 0, 0, 0);
        az[mt]  = __builtin_amdgcn_mfma_f32_16x16x32_bf16(ah[mt], w[12 + ks], az[mt], 0, 0, 0);
        ain[mt] = __builtin_amdgcn_mfma_f32_16x16x32_bf16(aa[mt], w[16 + ks], ain[mt], 0, 0, 0);
        ahn[mt] = __builtin_amdgcn_mfma_f32_16x16x32_bf16(ah[mt], w[20 + ks], ahn[mt], 0, 0, 0);
      }
    }

    // epilogue: h' = (1-z)*tanh(in + r*hn) + z*h_old ; h_old from LDS h-tile
    const __hip_bfloat16* hbase = &sA[cur][1][0];
    int row0 = tile * 32;
#pragma unroll
    for (int mt = 0; mt < 2; ++mt) {
#pragma unroll
      for (int j = 0; j < 4; ++j) {
        int lr = mt * 16 + (lane >> 4) * 4 + j;
        int grow = row0 + lr;
        if (grow < n) {
          float r  = 1.f / (1.f + __expf(-(ar[mt][j] + br)));
          float z  = 1.f / (1.f + __expf(-(az[mt][j] + bz)));
          float pa = ain[mt][j] + bin + r * (ahn[mt][j] + bhn);
          float e2 = __expf(2.f * pa);
          float nn = 1.f - 2.f / (e2 + 1.f);   // tanh, branch-free
          int ch2 = (col >> 3) ^ (lr & 7);
          float hold = __bfloat162float(hbase[lr * 128 + ch2 * 8 + (col & 7)]);
          float o = (1.f - z) * nn + z * hold;
          hb[(size_t)grow * 128 + col] = __float2bfloat16(o);
        }
      }
    }
    cur ^= 1;
  }
}

// ---------- per-node 1/max(||h||,eps) over bf16 state ----------
__global__ void k_norm(const __hip_bfloat16* __restrict__ hb, float* __restrict__ rnorm,
                       int n) {
  int node = (blockIdx.x * THREADS + threadIdx.x) >> 6;
  int lane = threadIdx.x & 63;
  if (node >= n) return;
  unsigned v = ((const unsigned*)hb)[(size_t)node * 64 + lane];
  float a = bf_lo(v), b = bf_hi(v);
  float s = a * a + b * b;
#pragma unroll
  for (int d = 1; d < 64; d <<= 1) s += __shfl_xor(s, d);
  if (lane == 0) rnorm[node] = 1.f / fmaxf(sqrtf(s), 1e-12f);
}

// ---------- per-graph max/mean pool of relu(hb * rnorm), split POOLS ways ----------
__global__ void k_pool(const __hip_bfloat16* __restrict__ hb, const float* __restrict__ rnorm,
                       const int* __restrict__ gs, const int* __restrict__ ge,
                       float* __restrict__ featp) {
  int g = blockIdx.x, sp = blockIdx.y;
  int c = threadIdx.x;  // 128
  int s = gs[g], e = ge[g];
  int len = e - s;
  int chunk = (len + POOLS - 1) / POOLS;
  int ns = s + sp * chunk;
  int ne = ns + chunk; if (ne > e) ne = e;
  float mx = 0.f, sm = 0.f;
  for (int nd = ns; nd < ne; ++nd) {
    float v = __bfloat162float(hb[(size_t)nd * 128 + c]) * rnorm[nd];
    v = fmaxf(v, 0.f);
    mx = fmaxf(mx, v);
    sm += v;
  }
  featp[((size_t)g * POOLS + sp) * 256 + c]       = mx;
  featp[((size_t)g * POOLS + sp) * 256 + 128 + c] = sm;
}

__global__ void k_pool2(const float* __restrict__ featp, const int* __restrict__ gs,
                        const int* __restrict__ ge, float* __restrict__ feat) {
  int g = blockIdx.x;
  int c = threadIdx.x;  // 256
  float mx = 0.f, sm = 0.f;
  for (int sp = 0; sp < POOLS; ++sp) {
    float v = featp[((size_t)g * POOLS + sp) * 256 + c];
    mx = fmaxf(mx, v);
    sm += v;
  }
  float cnt = fmaxf((float)(ge[g] - gs[g]), 1.f);
  feat[(size_t)g * 256 + c] = (c < 128) ? mx : (sm / cnt);
}

// ---------- final linear ----------
__global__ void k_final(const float* __restrict__ feat, const float* __restrict__ lin_w,
                        const float* __restrict__ lin_b, float* __restrict__ out) {
  int g = blockIdx.x;
  __shared__ float sf[256];
  sf[threadIdx.x] = feat[(size_t)g * 256 + threadIdx.x];
  __syncthreads();
  if (threadIdx.x < 10) {
    float s = lin_b[threadIdx.x];
    const float* w = lin_w + (size_t)threadIdx.x * 256;
#pragma unroll 8
    for (int c = 0; c < 256; ++c) s += sf[c] * w[c];
    out[(size_t)g * 10 + threadIdx.x] = s;
  }
}

extern "C" void kernel_launch(void* const* d_in, const int* in_sizes, int n_in,
                              void* d_out, int out_size, void* d_ws, size_t ws_size,
                              hipStream_t stream) {
  const float* x      = (const float*)d_in[0];
  const int*   ei     = (const int*)d_in[1];
  const int*   batch  = (const int*)d_in[2];
  const float* weight = (const float*)d_in[3];
  const float* w_ih   = (const float*)d_in[4];
  const float* w_hh   = (const float*)d_in[5];
  const float* b_ih   = (const float*)d_in[6];
  const float* b_hh   = (const float*)d_in[7];
  const float* lin_w  = (const float*)d_in[8];
  const float* lin_b  = (const float*)d_in[9];
  float* out = (float*)d_out;

  const int N = in_sizes[0] / 128;   // 100000
  const int E = in_sizes[1] / 2;     // 1600000
  const int G = out_size / 10;       // 64
  const int WP_PER_LAYER = 8 * 24 * 64 * 8;  // 98304

  char* wsc = (char*)d_ws;
  size_t off = 0;
  auto take = [&](size_t bytes) -> void* {
    void* p = wsc + off;
    off = align_up(off + bytes, 256);
    return p;
  };
  __hip_bfloat16*  hb     = (__hip_bfloat16*)take((size_t)N * 128 * 2);
  __hip_bfloat16*  agg    = (__hip_bfloat16*)take((size_t)N * 128 * 2);
  float*           Wc     = (float*)take((size_t)3 * 384 * 128 * 4);
  __hip_bfloat16*  Wp     = (__hip_bfloat16*)take((size_t)3 * WP_PER_LAYER * 2);
  float*           rnorm  = (float*)take((size_t)N * 4);
  int*             counts = (int*)take((size_t)N * 4);
  int*             offs   = (int*)take(((size_t)N + 1) * 4);
  int*             cursor = (int*)take((size_t)N * 4);
  int*             bsum   = (int*)take(512 * 4);
  int*             csr    = (int*)take((size_t)E * 4);
  int*             gs     = (int*)take((size_t)G * 4);
  int*             ge     = (int*)take((size_t)G * 4);
  float*           featp  = (float*)take((size_t)G * POOLS * 256 * 4);
  float*           feat   = (float*)take((size_t)G * 256 * 4);
  int*             flag   = (int*)take(256);
  (void)ws_size; (void)n_in;

  hipMemsetAsync(counts, 0, (size_t)N * 4, stream);
  hipMemsetAsync(gs, 0, (size_t)G * 4, stream);
  hipMemsetAsync(ge, 0, (size_t)G * 4, stream);

  k_detect<<<1, 64, 0, stream>>>(ei, flag);
  k_wc<<<(3 * 384 * 128 + THREADS - 1) / THREADS, THREADS, 0, stream>>>(weight, w_ih, Wc);
  k_wprep<<<(3 * WP_PER_LAYER + THREADS - 1) / THREADS, THREADS, 0, stream>>>(Wc, w_hh, Wp);
  k_init<<<(N * 32 + THREADS - 1) / THREADS, THREADS, 0, stream>>>(x, hb, N * 32);

  int nb = (N + 255) / 256;
  k_hist<<<(E + THREADS - 1) / THREADS, THREADS, 0, stream>>>(ei, counts, E, flag);
  k_scan1<<<nb, 256, 0, stream>>>(counts, offs, bsum, N);
  k_scan2<<<1, 512, 0, stream>>>(bsum, nb);
  k_scan3<<<nb, 256, 0, stream>>>(offs, cursor, bsum, N, E);
  k_fill<<<(E + THREADS - 1) / THREADS, THREADS, 0, stream>>>(ei, cursor, csr, E, flag);
  k_bounds<<<nb, 256, 0, stream>>>(batch, gs, ge, N, flag);

  const int ntiles = (N + 31) / 32;  // 3125
  for (int layer = 0; layer < 3; ++layer) {
    k_agg<<<(N + 3) / 4, THREADS, 0, stream>>>(hb, offs, csr, agg, N);
    k_gru_pers<<<256, 512, 0, stream>>>(
        agg, hb, Wp + (size_t)layer * WP_PER_LAYER, b_ih, b_hh, N, ntiles);
  }

  k_norm<<<(N + 3) / 4, THREADS, 0, stream>>>(hb, rnorm, N);
  k_pool<<<dim3(G, POOLS), 128, 0, stream>>>(hb, rnorm, gs, ge, featp);
  k_pool2<<<G, 256, 0, stream>>>(featp, gs, ge, feat);
  k_final<<<G, 256, 0, stream>>>(feat, lin_w, lin_b, out);
}

// Round 5
// 574.789 us; speedup vs baseline: 4.5076x; 1.0432x over previous
//
#include <hip/hip_runtime.h>
#include <hip/hip_bf16.h>

#define THREADS 256
#define POOLS 16
#define BKLOG 5
#define BKSZ 32   // nodes per bucket

typedef __attribute__((ext_vector_type(8))) short bf16x8;
typedef __attribute__((ext_vector_type(4))) float f32x4;

static inline size_t align_up(size_t x, size_t a) { return (x + a - 1) & ~(a - 1); }

__device__ __forceinline__ float bf_lo(unsigned v) { return __uint_as_float(v << 16); }
__device__ __forceinline__ float bf_hi(unsigned v) { return __uint_as_float(v & 0xffff0000u); }

__device__ __forceinline__ void gl_lds16(const void* g, void* l) {
  __builtin_amdgcn_global_load_lds(
      (const __attribute__((address_space(1))) unsigned*)g,
      (__attribute__((address_space(3))) unsigned*)l, 16, 0, 0);
}

// ---------- detect whether index inputs are stored as int64 (low/high words) ----------
__global__ void k_detect(const int* __restrict__ ei, int* __restrict__ flag) {
  if (blockIdx.x == 0 && threadIdx.x == 0) {
    int odd_zero = ((ei[1] | ei[3] | ei[5] | ei[7]) == 0);
    int even_nz  = ((ei[0] | ei[2] | ei[4] | ei[6]) != 0);
    flag[0] = (odd_zero && even_nz) ? 1 : 0;
  }
}

// ---------- Wc[i][j][k] = sum_t weight[i][k][t] * w_ih[j][t]  (3 x 384 x 128) ----------
__global__ void k_wc(const float* __restrict__ weight, const float* __restrict__ w_ih,
                     float* __restrict__ Wc) {
  int idx = blockIdx.x * blockDim.x + threadIdx.x;
  const int total = 3 * 384 * 128;
  if (idx >= total) return;
  int k = idx & 127;
  int j = (idx >> 7) % 384;
  int i = idx / (384 * 128);
  const float* wp = weight + (size_t)i * (128 * 128) + (size_t)k * 128;
  const float* ip = w_ih + (size_t)j * 128;
  float s = 0.f;
#pragma unroll 8
  for (int t = 0; t < 128; ++t) s += wp[t] * ip[t];
  Wc[idx] = s;
}

// ---------- pack weights: Wp[layer][wc(8)][f(24)][lane(64)][j(8)] bf16 ----------
__global__ void k_wprep(const float* __restrict__ Wc, const float* __restrict__ whh,
                        __hip_bfloat16* __restrict__ Wp) {
  int idx = blockIdx.x * blockDim.x + threadIdx.x;
  const int per_layer = 8 * 24 * 64 * 8;  // 98304
  if (idx >= 3 * per_layer) return;
  int layer = idx / per_layer;
  int rem = idx % per_layer;
  int j    = rem & 7;
  int lane = (rem >> 3) & 63;
  int f    = (rem >> 9) % 24;
  int wc   = rem / (24 * 512);
  int col  = wc * 16 + (lane & 15);
  int kl   = (lane >> 4) * 8 + j;
  float v;
  const float* wcl = Wc + (size_t)layer * 384 * 128;
  if (f < 8) {
    int ks = f;
    v = (ks < 4) ? wcl[(size_t)col * 128 + ks * 32 + kl]
                 : whh[(size_t)col * 128 + (ks - 4) * 32 + kl];
  } else if (f < 16) {
    int ks = f - 8;
    v = (ks < 4) ? wcl[(size_t)(128 + col) * 128 + ks * 32 + kl]
                 : whh[(size_t)(128 + col) * 128 + (ks - 4) * 32 + kl];
  } else if (f < 20) {
    int ks = f - 16;
    v = wcl[(size_t)(256 + col) * 128 + ks * 32 + kl];
  } else {
    int ks = f - 20;
    v = whh[(size_t)(256 + col) * 128 + ks * 32 + kl];
  }
  Wp[idx] = __float2bfloat16(v);
}

// ---------- hb = bf16(x) ----------
__global__ void k_init(const float* __restrict__ x, __hip_bfloat16* __restrict__ hb,
                       int total4) {
  int i = blockIdx.x * blockDim.x + threadIdx.x;
  if (i >= total4) return;
  float4 v = ((const float4*)x)[i];
  __hip_bfloat162 a, b;
  a.x = __float2bfloat16(v.x); a.y = __float2bfloat16(v.y);
  b.x = __float2bfloat16(v.z); b.y = __float2bfloat16(v.w);
  ((__hip_bfloat162*)hb)[2 * i]     = a;
  ((__hip_bfloat162*)hb)[2 * i + 1] = b;
}

// ---------- bucketed CSR build ----------
// Pass A: per-bucket edge histogram (LDS pre-aggregated)
__global__ void k_bhist(const int* __restrict__ ei, int* __restrict__ bcount,
                        int E, int NB, const int* __restrict__ flag) {
  __shared__ int lh[4096];
  int t = threadIdx.x;
  for (int i = t; i < NB; i += blockDim.x) lh[i] = 0;
  __syncthreads();
  int s64 = flag[0];
  int stride = gridDim.x * blockDim.x;
  for (int i = blockIdx.x * blockDim.x + t; i < E; i += stride) {
    size_t idx = s64 ? 2 * ((size_t)E + (size_t)i) : ((size_t)E + (size_t)i);
    atomicAdd(&lh[ei[idx] >> BKLOG], 1);
  }
  __syncthreads();
  for (int i = t; i < NB; i += blockDim.x)
    if (lh[i]) atomicAdd(&bcount[i], lh[i]);
}

__global__ void k_scan1(const int* __restrict__ counts, int* __restrict__ offs,
                        int* __restrict__ bsum, int n) {
  __shared__ int s[256];
  int b = blockIdx.x, t = threadIdx.x;
  int i = b * 256 + t;
  int v = (i < n) ? counts[i] : 0;
  s[t] = v;
  __syncthreads();
  for (int d = 1; d < 256; d <<= 1) {
    int x = (t >= d) ? s[t - d] : 0;
    __syncthreads();
    s[t] += x;
    __syncthreads();
  }
  if (i < n) offs[i] = s[t] - v;
  if (t == 255) bsum[b] = s[t];
}

__global__ void k_scan2(int* __restrict__ bsum, int nb) {
  __shared__ int s[512];
  int t = threadIdx.x;
  int v = (t < nb) ? bsum[t] : 0;
  s[t] = v;
  __syncthreads();
  for (int d = 1; d < 512; d <<= 1) {
    int x = (t >= d) ? s[t - d] : 0;
    __syncthreads();
    s[t] += x;
    __syncthreads();
  }
  if (t < nb) bsum[t] = s[t] - v;
}

__global__ void k_scan3(int* __restrict__ offs, int* __restrict__ cursor,
                        const int* __restrict__ bsum, int n, int total) {
  int i = blockIdx.x * blockDim.x + threadIdx.x;
  if (i < n) {
    int o = offs[i] + bsum[i >> 8];
    offs[i] = o;
    cursor[i] = o;
  }
  if (i == 0) offs[n] = total;
}

// Pass B: scatter packed (src<<5 | dst&31) into bucket-contiguous scratch
__global__ void k_bscatter(const int* __restrict__ ei, int* __restrict__ bcursor,
                           int* __restrict__ scratch, int E,
                           const int* __restrict__ flag) {
  int i = blockIdx.x * blockDim.x + threadIdx.x;
  if (i >= E) return;
  int s64 = flag[0];
  int sv = ei[s64 ? 2 * (size_t)i : (size_t)i];
  int dv = ei[s64 ? 2 * ((size_t)E + (size_t)i) : ((size_t)E + (size_t)i)];
  int pos = atomicAdd(&bcursor[dv >> BKLOG], 1);
  scratch[pos] = (sv << BKLOG) | (dv & (BKSZ - 1));
}

// Pass C: per bucket, build node offs + exact csr (bucket-local writes)
__global__ void k_bcsr(const int* __restrict__ scratch, const int* __restrict__ boffs,
                       int* __restrict__ offs, int* __restrict__ csr,
                       int n, int NB, int E) {
  __shared__ int lcur[BKSZ];
  __shared__ int lcnt[BKSZ];
  int b = blockIdx.x, t = threadIdx.x;
  int s = boffs[b], e = boffs[b + 1];
  if (t < BKSZ) lcnt[t] = 0;
  __syncthreads();
  for (int i = s + t; i < e; i += blockDim.x)
    atomicAdd(&lcnt[scratch[i] & (BKSZ - 1)], 1);
  __syncthreads();
  if (t == 0) {
    int run = 0;
#pragma unroll
    for (int i = 0; i < BKSZ; ++i) {
      lcur[i] = run;
      int node = b * BKSZ + i;
      if (node < n) offs[node] = s + run;
      run += lcnt[i];
    }
    if (b == NB - 1) offs[n] = E;
  }
  __syncthreads();
  for (int i = s + t; i < e; i += blockDim.x) {
    int v = scratch[i];
    int pos = atomicAdd(&lcur[v & (BKSZ - 1)], 1);
    csr[s + pos] = v >> BKLOG;
  }
}

__global__ void k_bounds(const int* __restrict__ batch, int* __restrict__ gs,
                         int* __restrict__ ge, int n, const int* __restrict__ flag) {
  int i = blockIdx.x * blockDim.x + threadIdx.x;
  if (i >= n) return;
  int s64 = flag[0];
  int b  = batch[s64 ? 2 * (size_t)i : (size_t)i];
  int bp = (i > 0)     ? batch[s64 ? 2 * (size_t)(i - 1) : (size_t)(i - 1)] : -1;
  int bn = (i < n - 1) ? batch[s64 ? 2 * (size_t)(i + 1) : (size_t)(i + 1)] : -1;
  if (i == 0 || bp != b) gs[b] = i;
  if (i == n - 1 || bn != b) ge[b] = i + 1;
}

// ---------- aggregation: agg[n] = sum over in-edges of hb[src]; deep-MLP gather ----------
__global__ void k_agg(const __hip_bfloat16* __restrict__ hb, const int* __restrict__ offs,
                      const int* __restrict__ csr, __hip_bfloat16* __restrict__ agg, int n) {
  int node = (blockIdx.x * THREADS + threadIdx.x) >> 6;
  int lane = threadIdx.x & 63;
  if (node >= n) return;
  const unsigned* base = (const unsigned*)hb + lane;  // row stride = 64 uints
  int s = offs[node], e = offs[node + 1];
  float ax0 = 0.f, ay0 = 0.f, ax1 = 0.f, ay1 = 0.f;
  float ax2 = 0.f, ay2 = 0.f, ax3 = 0.f, ay3 = 0.f;
  for (int bs = s; bs < e; bs += 64) {
    int cnt = e - bs; if (cnt > 64) cnt = 64;
    int idx = csr[bs + ((lane < cnt) ? lane : (cnt - 1))];  // one coalesced load
    int j = 0;
    for (; j + 8 <= cnt; j += 8) {
      int s0 = __shfl(idx, j + 0), s1 = __shfl(idx, j + 1);
      int s2 = __shfl(idx, j + 2), s3 = __shfl(idx, j + 3);
      int s4 = __shfl(idx, j + 4), s5 = __shfl(idx, j + 5);
      int s6 = __shfl(idx, j + 6), s7 = __shfl(idx, j + 7);
      unsigned v0 = base[(size_t)s0 * 64], v1 = base[(size_t)s1 * 64];
      unsigned v2 = base[(size_t)s2 * 64], v3 = base[(size_t)s3 * 64];
      unsigned v4 = base[(size_t)s4 * 64], v5 = base[(size_t)s5 * 64];
      unsigned v6 = base[(size_t)s6 * 64], v7 = base[(size_t)s7 * 64];
      ax0 += bf_lo(v0); ay0 += bf_hi(v0); ax1 += bf_lo(v1); ay1 += bf_hi(v1);
      ax2 += bf_lo(v2); ay2 += bf_hi(v2); ax3 += bf_lo(v3); ay3 += bf_hi(v3);
      ax0 += bf_lo(v4); ay0 += bf_hi(v4); ax1 += bf_lo(v5); ay1 += bf_hi(v5);
      ax2 += bf_lo(v6); ay2 += bf_hi(v6); ax3 += bf_lo(v7); ay3 += bf_hi(v7);
    }
    for (; j < cnt; ++j) {
      unsigned v = base[(size_t)__shfl(idx, j) * 64];
      ax0 += bf_lo(v); ay0 += bf_hi(v);
    }
  }
  float ax = (ax0 + ax1) + (ax2 + ax3);
  float ay = (ay0 + ay1) + (ay2 + ay3);
  __hip_bfloat162 o;
  o.x = __float2bfloat16(ax);
  o.y = __float2bfloat16(ay);
  *(__hip_bfloat162*)(agg + (size_t)node * 128 + lane * 2) = o;
}

// ---------- persistent MFMA GRU: hb = GRUCell(agg, hb) in place ----------
// 256 threads = 4 waves; block owns (tile, col-half): 32 rows x 64 cols.
// grid = 512 -> 2 blocks/CU so one block computes while the other stages.
// Weights register-resident (24 bf16x8/lane). Double-buffered LDS A-staging
// via global_load_lds with pre-swizzled source (XOR-chunk swizzle).
__launch_bounds__(256, 2)
__global__ void k_gru_pers(const __hip_bfloat16* __restrict__ agg,
                           __hip_bfloat16* __restrict__ hb,
                           const __hip_bfloat16* __restrict__ Wp,  // layer slice
                           const float* __restrict__ b_ih,
                           const float* __restrict__ b_hh,
                           int n, int ntiles) {
  __shared__ __align__(16) __hip_bfloat16 sA[2][2][32 * 128];  // [dbuf][agg|h] 32KB
  const int t    = threadIdx.x;
  const int lane = t & 63;
  const int wc   = t >> 6;                 // wave 0..3
  const int half = blockIdx.x & 1;         // col half (fixed per block)
  const int wf   = half * 4 + wc;          // full col-tile id 0..7

  // ---- weights -> registers (once) ----
  bf16x8 w[24];
  {
    const bf16x8* wp = (const bf16x8*)Wp + (size_t)(wf * 24) * 64 + lane;
#pragma unroll
    for (int f = 0; f < 24; ++f) w[f] = wp[(size_t)f * 64];
  }
  // ---- per-lane biases ----
  const int col = half * 64 + wc * 16 + (lane & 15);
  const float br  = b_ih[col] + b_hh[col];
  const float bz  = b_ih[128 + col] + b_hh[128 + col];
  const float bin = b_ih[256 + col];
  const float bhn = b_hh[256 + col];

  auto stage = [&](int buf, int tileIdx) {
    const char* ga = (const char*)agg + (size_t)tileIdx * 8192;
    const char* gh = (const char*)hb  + (size_t)tileIdx * 8192;
#pragma unroll
    for (int p = 0; p < 2; ++p) {
      int slot = p * 256 + t;
      int row  = slot >> 4;
      int sc   = (slot & 15) ^ (row & 7);
      int gb   = row * 256 + sc * 16;
      char* la = (char*)&sA[buf][0][0] + p * 4096 + wc * 1024;  // wave-uniform base
      char* lh = (char*)&sA[buf][1][0] + p * 4096 + wc * 1024;
      gl_lds16(ga + gb, la);
      gl_lds16(gh + gb, lh);
    }
  };

  const int tstep = gridDim.x >> 1;
  int tile = blockIdx.x >> 1;
  if (tile < ntiles) stage(0, tile);
  int cur = 0;

  for (; tile < ntiles; tile += tstep) {
    __syncthreads();   // buf[cur] staged; prev iter's LDS reads done
    int nxt = tile + tstep;
    if (nxt < ntiles) stage(cur ^ 1, nxt);

    const char* cb = (const char*)&sA[cur][0][0];
    f32x4 ar[2], az[2], ain[2], ahn[2];
#pragma unroll
    for (int mt = 0; mt < 2; ++mt) {
      ar[mt] = (f32x4){0.f, 0.f, 0.f, 0.f};
      az[mt] = (f32x4){0.f, 0.f, 0.f, 0.f};
      ain[mt] = (f32x4){0.f, 0.f, 0.f, 0.f};
      ahn[mt] = (f32x4){0.f, 0.f, 0.f, 0.f};
    }

#pragma unroll
    for (int ks = 0; ks < 4; ++ks) {
      bf16x8 aa[2], ah[2];
#pragma unroll
      for (int mt = 0; mt < 2; ++mt) {
        int row = mt * 16 + (lane & 15);
        int ch  = (ks * 4 + (lane >> 4)) ^ (row & 7);
        aa[mt] = *(const bf16x8*)(cb + row * 256 + ch * 16);
        ah[mt] = *(const bf16x8*)(cb + 8192 + row * 256 + ch * 16);
      }
#pragma unroll
      for (int mt = 0; mt < 2; ++mt) {
        ar[mt]  = __builtin_amdgcn_mfma_f32_16x16x32_bf16(aa[mt], w[ks],      ar[mt], 0, 0, 0);
        ar[mt]  = __builtin_amdgcn_mfma_f32_16x16x32_bf16(ah[mt], w[4 + ks],  ar[mt], 0, 0, 0);
        az[mt]  = __builtin_amdgcn_mfma_f32_16x16x32_bf16(aa[mt], w[8 + ks],  az[mt], 0, 0, 0);
        az[mt]  = __builtin_amdgcn_mfma_f32_16x16x32_bf16(ah[mt], w[12 + ks], az[mt], 0, 0, 0);
        ain[mt] = __builtin_amdgcn_mfma_f32_16x16x32_bf16(aa[mt], w[16 + ks], ain[mt], 0, 0, 0);
        ahn[mt] = __builtin_amdgcn_mfma_f32_16x16x32_bf16(ah[mt], w[20 + ks], ahn[mt], 0, 0, 0);
      }
    }

    // epilogue: h' = (1-z)*tanh(in + r*hn) + z*h_old ; h_old from LDS h-tile
    const __hip_bfloat16* hbase = &sA[cur][1][0];
    int row0 = tile * 32;
#pragma unroll
    for (int mt = 0; mt < 2; ++mt) {
#pragma unroll
      for (int j = 0; j < 4; ++j) {
        int lr = mt * 16 + (lane >> 4) * 4 + j;
        int grow = row0 + lr;
        if (grow < n) {
          float r  = 1.f / (1.f + __expf(-(ar[mt][j] + br)));
          float z  = 1.f / (1.f + __expf(-(az[mt][j] + bz)));
          float pa = ain[mt][j] + bin + r * (ahn[mt][j] + bhn);
          float e2 = __expf(2.f * pa);
          float nn = 1.f - 2.f / (e2 + 1.f);   // tanh, branch-free
          int ch2 = (col >> 3) ^ (lr & 7);
          float hold = __bfloat162float(hbase[lr * 128 + ch2 * 8 + (col & 7)]);
          float o = (1.f - z) * nn + z * hold;
          hb[(size_t)grow * 128 + col] = __float2bfloat16(o);
        }
      }
    }
    cur ^= 1;
  }
}

// ---------- per-node 1/max(||h||,eps) over bf16 state ----------
__global__ void k_norm(const __hip_bfloat16* __restrict__ hb, float* __restrict__ rnorm,
                       int n) {
  int node = (blockIdx.x * THREADS + threadIdx.x) >> 6;
  int lane = threadIdx.x & 63;
  if (node >= n) return;
  unsigned v = ((const unsigned*)hb)[(size_t)node * 64 + lane];
  float a = bf_lo(v), b = bf_hi(v);
  float s = a * a + b * b;
#pragma unroll
  for (int d = 1; d < 64; d <<= 1) s += __shfl_xor(s, d);
  if (lane == 0) rnorm[node] = 1.f / fmaxf(sqrtf(s), 1e-12f);
}

// ---------- per-graph max/mean pool of relu(hb * rnorm), split POOLS ways ----------
__global__ void k_pool(const __hip_bfloat16* __restrict__ hb, const float* __restrict__ rnorm,
                       const int* __restrict__ gs, const int* __restrict__ ge,
                       float* __restrict__ featp) {
  int g = blockIdx.x, sp = blockIdx.y;
  int c = threadIdx.x;  // 128
  int s = gs[g], e = ge[g];
  int len = e - s;
  int chunk = (len + POOLS - 1) / POOLS;
  int ns = s + sp * chunk;
  int ne = ns + chunk; if (ne > e) ne = e;
  float mx = 0.f, sm = 0.f;
  for (int nd = ns; nd < ne; ++nd) {
    float v = __bfloat162float(hb[(size_t)nd * 128 + c]) * rnorm[nd];
    v = fmaxf(v, 0.f);
    mx = fmaxf(mx, v);
    sm += v;
  }
  featp[((size_t)g * POOLS + sp) * 256 + c]       = mx;
  featp[((size_t)g * POOLS + sp) * 256 + 128 + c] = sm;
}

__global__ void k_pool2(const float* __restrict__ featp, const int* __restrict__ gs,
                        const int* __restrict__ ge, float* __restrict__ feat) {
  int g = blockIdx.x;
  int c = threadIdx.x;  // 256
  float mx = 0.f, sm = 0.f;
  for (int sp = 0; sp < POOLS; ++sp) {
    float v = featp[((size_t)g * POOLS + sp) * 256 + c];
    mx = fmaxf(mx, v);
    sm += v;
  }
  float cnt = fmaxf((float)(ge[g] - gs[g]), 1.f);
  feat[(size_t)g * 256 + c] = (c < 128) ? mx : (sm / cnt);
}

// ---------- final linear ----------
__global__ void k_final(const float* __restrict__ feat, const float* __restrict__ lin_w,
                        const float* __restrict__ lin_b, float* __restrict__ out) {
  int g = blockIdx.x;
  __shared__ float sf[256];
  sf[threadIdx.x] = feat[(size_t)g * 256 + threadIdx.x];
  __syncthreads();
  if (threadIdx.x < 10) {
    float s = lin_b[threadIdx.x];
    const float* w = lin_w + (size_t)threadIdx.x * 256;
#pragma unroll 8
    for (int c = 0; c < 256; ++c) s += sf[c] * w[c];
    out[(size_t)g * 10 + threadIdx.x] = s;
  }
}

extern "C" void kernel_launch(void* const* d_in, const int* in_sizes, int n_in,
                              void* d_out, int out_size, void* d_ws, size_t ws_size,
                              hipStream_t stream) {
  const float* x      = (const float*)d_in[0];
  const int*   ei     = (const int*)d_in[1];
  const int*   batch  = (const int*)d_in[2];
  const float* weight = (const float*)d_in[3];
  const float* w_ih   = (const float*)d_in[4];
  const float* w_hh   = (const float*)d_in[5];
  const float* b_ih   = (const float*)d_in[6];
  const float* b_hh   = (const float*)d_in[7];
  const float* lin_w  = (const float*)d_in[8];
  const float* lin_b  = (const float*)d_in[9];
  float* out = (float*)d_out;

  const int N = in_sizes[0] / 128;   // 100000
  const int E = in_sizes[1] / 2;     // 1600000
  const int G = out_size / 10;       // 64
  const int NB = (N + BKSZ - 1) / BKSZ;  // 3125 buckets
  const int WP_PER_LAYER = 8 * 24 * 64 * 8;  // 98304

  char* wsc = (char*)d_ws;
  size_t off = 0;
  auto take = [&](size_t bytes) -> void* {
    void* p = wsc + off;
    off = align_up(off + bytes, 256);
    return p;
  };
  __hip_bfloat16*  hb     = (__hip_bfloat16*)take((size_t)N * 128 * 2);
  __hip_bfloat16*  agg    = (__hip_bfloat16*)take((size_t)N * 128 * 2);
  float*           Wc     = (float*)take((size_t)3 * 384 * 128 * 4);
  __hip_bfloat16*  Wp     = (__hip_bfloat16*)take((size_t)3 * WP_PER_LAYER * 2);
  float*           rnorm  = (float*)take((size_t)N * 4);
  int*             offs   = (int*)take(((size_t)N + 1) * 4);
  int*             bcount = (int*)take((size_t)NB * 4);
  int*             boffs  = (int*)take(((size_t)NB + 1) * 4);
  int*             bcursor= (int*)take((size_t)NB * 4);
  int*             bsum   = (int*)take(512 * 4);
  int*             csr    = (int*)take((size_t)E * 4);
  int*             gs     = (int*)take((size_t)G * 4);
  int*             ge     = (int*)take((size_t)G * 4);
  float*           featp  = (float*)take((size_t)G * POOLS * 256 * 4);
  float*           feat   = (float*)take((size_t)G * 256 * 4);
  int*             flag   = (int*)take(256);
  int*             scratch = (int*)agg;   // agg not live during CSR build
  (void)ws_size; (void)n_in;

  hipMemsetAsync(bcount, 0, (size_t)NB * 4, stream);
  hipMemsetAsync(gs, 0, (size_t)G * 4, stream);
  hipMemsetAsync(ge, 0, (size_t)G * 4, stream);

  k_detect<<<1, 64, 0, stream>>>(ei, flag);
  k_wc<<<(3 * 384 * 128 + THREADS - 1) / THREADS, THREADS, 0, stream>>>(weight, w_ih, Wc);
  k_wprep<<<(3 * WP_PER_LAYER + THREADS - 1) / THREADS, THREADS, 0, stream>>>(Wc, w_hh, Wp);
  k_init<<<(N * 32 + THREADS - 1) / THREADS, THREADS, 0, stream>>>(x, hb, N * 32);

  // bucketed CSR build
  int nbb = (NB + 255) / 256;
  k_bhist<<<128, THREADS, 0, stream>>>(ei, bcount, E, NB, flag);
  k_scan1<<<nbb, 256, 0, stream>>>(bcount, boffs, bsum, NB);
  k_scan2<<<1, 512, 0, stream>>>(bsum, nbb);
  k_scan3<<<nbb, 256, 0, stream>>>(boffs, bcursor, bsum, NB, E);
  k_bscatter<<<(E + THREADS - 1) / THREADS, THREADS, 0, stream>>>(ei, bcursor, scratch, E, flag);
  k_bcsr<<<NB, THREADS, 0, stream>>>(scratch, boffs, offs, csr, N, NB, E);
  k_bounds<<<(N + 255) / 256, 256, 0, stream>>>(batch, gs, ge, N, flag);

  const int ntiles = (N + 31) / 32;  // 3125
  for (int layer = 0; layer < 3; ++layer) {
    k_agg<<<(N + 3) / 4, THREADS, 0, stream>>>(hb, offs, csr, agg, N);
    k_gru_pers<<<512, 256, 0, stream>>>(
        agg, hb, Wp + (size_t)layer * WP_PER_LAYER, b_ih, b_hh, N, ntiles);
  }

  k_norm<<<(N + 3) / 4, THREADS, 0, stream>>>(hb, rnorm, N);
  k_pool<<<dim3(G, POOLS), 128, 0, stream>>>(hb, rnorm, gs, ge, featp);
  k_pool2<<<G, 256, 0, stream>>>(featp, gs, ge, feat);
  k_final<<<G, 256, 0, stream>>>(feat, lin_w, lin_b, out);
}

// Round 6
// 460.770 us; speedup vs baseline: 5.6230x; 1.2475x over previous
//
#include <hip/hip_runtime.h>
#include <hip/hip_bf16.h>

#define THREADS 256
#define POOLS 16
#define BK2LOG 9
#define BK2SZ 512         // nodes per coarse bucket
#define EPT 16            // edges per thread in scatter
#define CHUNK (EPT * 256) // edges per scatter block

typedef __attribute__((ext_vector_type(8))) short bf16x8;
typedef __attribute__((ext_vector_type(4))) float f32x4;

static inline size_t align_up(size_t x, size_t a) { return (x + a - 1) & ~(a - 1); }

__device__ __forceinline__ float bf_lo(unsigned v) { return __uint_as_float(v << 16); }
__device__ __forceinline__ float bf_hi(unsigned v) { return __uint_as_float(v & 0xffff0000u); }

__device__ __forceinline__ void gl_lds16(const void* g, void* l) {
  __builtin_amdgcn_global_load_lds(
      (const __attribute__((address_space(1))) unsigned*)g,
      (__attribute__((address_space(3))) unsigned*)l, 16, 0, 0);
}

// ---------- detect whether index inputs are stored as int64 (low/high words) ----------
__global__ void k_detect(const int* __restrict__ ei, int* __restrict__ flag) {
  if (blockIdx.x == 0 && threadIdx.x == 0) {
    int odd_zero = ((ei[1] | ei[3] | ei[5] | ei[7]) == 0);
    int even_nz  = ((ei[0] | ei[2] | ei[4] | ei[6]) != 0);
    flag[0] = (odd_zero && even_nz) ? 1 : 0;
  }
}

// ---------- Wc[i][j][k] = sum_t weight[i][k][t] * w_ih[j][t]  (3 x 384 x 128) ----------
__global__ void k_wc(const float* __restrict__ weight, const float* __restrict__ w_ih,
                     float* __restrict__ Wc) {
  int idx = blockIdx.x * blockDim.x + threadIdx.x;
  const int total = 3 * 384 * 128;
  if (idx >= total) return;
  int k = idx & 127;
  int j = (idx >> 7) % 384;
  int i = idx / (384 * 128);
  const float* wp = weight + (size_t)i * (128 * 128) + (size_t)k * 128;
  const float* ip = w_ih + (size_t)j * 128;
  float s = 0.f;
#pragma unroll 8
  for (int t = 0; t < 128; ++t) s += wp[t] * ip[t];
  Wc[idx] = s;
}

// ---------- pack weights: Wp[layer][wc(8)][f(24)][lane(64)][j(8)] bf16 ----------
__global__ void k_wprep(const float* __restrict__ Wc, const float* __restrict__ whh,
                        __hip_bfloat16* __restrict__ Wp) {
  int idx = blockIdx.x * blockDim.x + threadIdx.x;
  const int per_layer = 8 * 24 * 64 * 8;  // 98304
  if (idx >= 3 * per_layer) return;
  int layer = idx / per_layer;
  int rem = idx % per_layer;
  int j    = rem & 7;
  int lane = (rem >> 3) & 63;
  int f    = (rem >> 9) % 24;
  int wc   = rem / (24 * 512);
  int col  = wc * 16 + (lane & 15);
  int kl   = (lane >> 4) * 8 + j;
  float v;
  const float* wcl = Wc + (size_t)layer * 384 * 128;
  if (f < 8) {
    int ks = f;
    v = (ks < 4) ? wcl[(size_t)col * 128 + ks * 32 + kl]
                 : whh[(size_t)col * 128 + (ks - 4) * 32 + kl];
  } else if (f < 16) {
    int ks = f - 8;
    v = (ks < 4) ? wcl[(size_t)(128 + col) * 128 + ks * 32 + kl]
                 : whh[(size_t)(128 + col) * 128 + (ks - 4) * 32 + kl];
  } else if (f < 20) {
    int ks = f - 16;
    v = wcl[(size_t)(256 + col) * 128 + ks * 32 + kl];
  } else {
    int ks = f - 20;
    v = whh[(size_t)(256 + col) * 128 + ks * 32 + kl];
  }
  Wp[idx] = __float2bfloat16(v);
}

// ---------- hb = bf16(x) ----------
__global__ void k_init(const float* __restrict__ x, __hip_bfloat16* __restrict__ hb,
                       int total4) {
  int i = blockIdx.x * blockDim.x + threadIdx.x;
  if (i >= total4) return;
  float4 v = ((const float4*)x)[i];
  __hip_bfloat162 a, b;
  a.x = __float2bfloat16(v.x); a.y = __float2bfloat16(v.y);
  b.x = __float2bfloat16(v.z); b.y = __float2bfloat16(v.w);
  ((__hip_bfloat162*)hb)[2 * i]     = a;
  ((__hip_bfloat162*)hb)[2 * i + 1] = b;
}

// ---------- two-level CSR build ----------
// Pass A: coarse-bucket histogram (196 buckets of 512 nodes)
__global__ void k_bhist(const int* __restrict__ ei, int* __restrict__ bcount,
                        int E, int NB2, const int* __restrict__ flag) {
  __shared__ int lh[256];
  int t = threadIdx.x;
  lh[t] = 0;
  __syncthreads();
  int s64 = flag[0];
  int stride = gridDim.x * blockDim.x;
  for (int i = blockIdx.x * blockDim.x + t; i < E; i += stride) {
    size_t idx = s64 ? 2 * ((size_t)E + (size_t)i) : ((size_t)E + (size_t)i);
    atomicAdd(&lh[ei[idx] >> BK2LOG], 1);
  }
  __syncthreads();
  if (t < NB2 && lh[t]) atomicAdd(&bcount[t], lh[t]);
}

// single-block scan over NB2 (<=256) buckets -> boffs (exclusive) + bcursor
__global__ void k_bscan(const int* __restrict__ bcount, int* __restrict__ boffs,
                        int* __restrict__ bcursor, int NB2, int E) {
  __shared__ int s[256];
  int t = threadIdx.x;
  int v = (t < NB2) ? bcount[t] : 0;
  s[t] = v;
  __syncthreads();
  for (int d = 1; d < 256; d <<= 1) {
    int x = (t >= d) ? s[t - d] : 0;
    __syncthreads();
    s[t] += x;
    __syncthreads();
  }
  if (t < NB2) {
    int o = s[t] - v;
    boffs[t] = o;
    bcursor[t] = o;
  }
  if (t == 0) boffs[NB2] = E;
}

// Pass B: block-presorted scatter. Each block reserves one contiguous run per
// bucket (single-writer cachelines) and scatters packed (src<<9 | dst&511).
__global__ void k_bscatter(const int* __restrict__ ei, int* __restrict__ bcursor,
                           int* __restrict__ scratch, int E,
                           const int* __restrict__ flag) {
  __shared__ int lcnt[256];
  __shared__ int gbase[256];
  int t = threadIdx.x;
  lcnt[t] = 0;
  __syncthreads();
  int s64 = flag[0];
  int base = blockIdx.x * CHUNK;
  int pk[EPT], bk[EPT];
#pragma unroll
  for (int e = 0; e < EPT; ++e) {
    int i = base + e * 256 + t;
    if (i < E) {
      int sv = ei[s64 ? 2 * (size_t)i : (size_t)i];
      int dv = ei[s64 ? 2 * ((size_t)E + (size_t)i) : ((size_t)E + (size_t)i)];
      bk[e] = dv >> BK2LOG;
      pk[e] = (sv << BK2LOG) | (dv & (BK2SZ - 1));
      atomicAdd(&lcnt[bk[e]], 1);
    } else {
      bk[e] = -1;
    }
  }
  __syncthreads();
  int c = lcnt[t];
  if (c > 0) gbase[t] = atomicAdd(&bcursor[t], c);
  __syncthreads();
  lcnt[t] = 0;   // reuse as local cursor
  __syncthreads();
#pragma unroll
  for (int e = 0; e < EPT; ++e) {
    if (bk[e] >= 0) {
      int li = atomicAdd(&lcnt[bk[e]], 1);
      scratch[gbase[bk[e]] + li] = pk[e];
    }
  }
}

// Pass C: per bucket, node-level offsets + exact csr (bucket-private region)
__global__ void k_bcsr(const int* __restrict__ scratch, const int* __restrict__ boffs,
                       int* __restrict__ offs, int* __restrict__ csr,
                       int n, int NB2, int E) {
  __shared__ int lcnt[BK2SZ];
  __shared__ int lcur[BK2SZ];
  int b = blockIdx.x, t = threadIdx.x;  // 256 threads
  int s = boffs[b], e = boffs[b + 1];
  lcnt[t] = 0;
  lcnt[t + 256] = 0;
  __syncthreads();
  for (int i = s + t; i < e; i += 256)
    atomicAdd(&lcnt[scratch[i] & (BK2SZ - 1)], 1);
  __syncthreads();
  // exclusive scan of 512 counters by wave 0 (8 chunks of 64, shfl scan)
  if (t < 64) {
    int run = 0;
    for (int cch = 0; cch < 8; ++cch) {
      int idx = cch * 64 + t;
      int vv = lcnt[idx];
      int inc = vv;
#pragma unroll
      for (int d = 1; d < 64; d <<= 1) {
        int x = __shfl_up(inc, d);
        if (t >= d) inc += x;
      }
      lcur[idx] = run + inc - vv;
      run += __shfl(inc, 63);
    }
  }
  __syncthreads();
  for (int i = t; i < BK2SZ; i += 256) {
    int node = b * BK2SZ + i;
    if (node < n) offs[node] = s + lcur[i];
  }
  if (b == NB2 - 1 && t == 0) offs[n] = E;
  __syncthreads();
  for (int i = s + t; i < e; i += 256) {
    int v = scratch[i];
    int nl = v & (BK2SZ - 1);
    int pos = atomicAdd(&lcur[nl], 1);
    csr[s + pos] = v >> BK2LOG;
  }
}

__global__ void k_bounds(const int* __restrict__ batch, int* __restrict__ gs,
                         int* __restrict__ ge, int n, const int* __restrict__ flag) {
  int i = blockIdx.x * blockDim.x + threadIdx.x;
  if (i >= n) return;
  int s64 = flag[0];
  int b  = batch[s64 ? 2 * (size_t)i : (size_t)i];
  int bp = (i > 0)     ? batch[s64 ? 2 * (size_t)(i - 1) : (size_t)(i - 1)] : -1;
  int bn = (i < n - 1) ? batch[s64 ? 2 * (size_t)(i + 1) : (size_t)(i + 1)] : -1;
  if (i == 0 || bp != b) gs[b] = i;
  if (i == n - 1 || bn != b) ge[b] = i + 1;
}

// ---------- aggregation: agg[n] = sum over in-edges of hb[src]; deep-MLP gather ----------
__global__ void k_agg(const __hip_bfloat16* __restrict__ hb, const int* __restrict__ offs,
                      const int* __restrict__ csr, __hip_bfloat16* __restrict__ agg, int n) {
  int node = (blockIdx.x * THREADS + threadIdx.x) >> 6;
  int lane = threadIdx.x & 63;
  if (node >= n) return;
  const unsigned* base = (const unsigned*)hb + lane;  // row stride = 64 uints
  int s = offs[node], e = offs[node + 1];
  float ax0 = 0.f, ay0 = 0.f, ax1 = 0.f, ay1 = 0.f;
  float ax2 = 0.f, ay2 = 0.f, ax3 = 0.f, ay3 = 0.f;
  for (int bs = s; bs < e; bs += 64) {
    int cnt = e - bs; if (cnt > 64) cnt = 64;
    int idx = csr[bs + ((lane < cnt) ? lane : (cnt - 1))];  // one coalesced load
    int j = 0;
    for (; j + 8 <= cnt; j += 8) {
      int s0 = __shfl(idx, j + 0), s1 = __shfl(idx, j + 1);
      int s2 = __shfl(idx, j + 2), s3 = __shfl(idx, j + 3);
      int s4 = __shfl(idx, j + 4), s5 = __shfl(idx, j + 5);
      int s6 = __shfl(idx, j + 6), s7 = __shfl(idx, j + 7);
      unsigned v0 = base[(size_t)s0 * 64], v1 = base[(size_t)s1 * 64];
      unsigned v2 = base[(size_t)s2 * 64], v3 = base[(size_t)s3 * 64];
      unsigned v4 = base[(size_t)s4 * 64], v5 = base[(size_t)s5 * 64];
      unsigned v6 = base[(size_t)s6 * 64], v7 = base[(size_t)s7 * 64];
      ax0 += bf_lo(v0); ay0 += bf_hi(v0); ax1 += bf_lo(v1); ay1 += bf_hi(v1);
      ax2 += bf_lo(v2); ay2 += bf_hi(v2); ax3 += bf_lo(v3); ay3 += bf_hi(v3);
      ax0 += bf_lo(v4); ay0 += bf_hi(v4); ax1 += bf_lo(v5); ay1 += bf_hi(v5);
      ax2 += bf_lo(v6); ay2 += bf_hi(v6); ax3 += bf_lo(v7); ay3 += bf_hi(v7);
    }
    for (; j < cnt; ++j) {
      unsigned v = base[(size_t)__shfl(idx, j) * 64];
      ax0 += bf_lo(v); ay0 += bf_hi(v);
    }
  }
  float ax = (ax0 + ax1) + (ax2 + ax3);
  float ay = (ay0 + ay1) + (ay2 + ay3);
  __hip_bfloat162 o;
  o.x = __float2bfloat16(ax);
  o.y = __float2bfloat16(ay);
  *(__hip_bfloat162*)(agg + (size_t)node * 128 + lane * 2) = o;
}

// ---------- persistent MFMA GRU: hb = GRUCell(agg, hb) in place ----------
__launch_bounds__(256, 2)
__global__ void k_gru_pers(const __hip_bfloat16* __restrict__ agg,
                           __hip_bfloat16* __restrict__ hb,
                           const __hip_bfloat16* __restrict__ Wp,  // layer slice
                           const float* __restrict__ b_ih,
                           const float* __restrict__ b_hh,
                           int n, int ntiles) {
  __shared__ __align__(16) __hip_bfloat16 sA[2][2][32 * 128];  // [dbuf][agg|h] 32KB
  const int t    = threadIdx.x;
  const int lane = t & 63;
  const int wc   = t >> 6;                 // wave 0..3
  const int half = blockIdx.x & 1;         // col half (fixed per block)
  const int wf   = half * 4 + wc;          // full col-tile id 0..7

  // ---- weights -> registers (once) ----
  bf16x8 w[24];
  {
    const bf16x8* wp = (const bf16x8*)Wp + (size_t)(wf * 24) * 64 + lane;
#pragma unroll
    for (int f = 0; f < 24; ++f) w[f] = wp[(size_t)f * 64];
  }
  // ---- per-lane biases ----
  const int col = half * 64 + wc * 16 + (lane & 15);
  const float br  = b_ih[col] + b_hh[col];
  const float bz  = b_ih[128 + col] + b_hh[128 + col];
  const float bin = b_ih[256 + col];
  const float bhn = b_hh[256 + col];

  auto stage = [&](int buf, int tileIdx) {
    const char* ga = (const char*)agg + (size_t)tileIdx * 8192;
    const char* gh = (const char*)hb  + (size_t)tileIdx * 8192;
#pragma unroll
    for (int p = 0; p < 2; ++p) {
      int slot = p * 256 + t;
      int row  = slot >> 4;
      int sc   = (slot & 15) ^ (row & 7);
      int gb   = row * 256 + sc * 16;
      char* la = (char*)&sA[buf][0][0] + p * 4096 + wc * 1024;  // wave-uniform base
      char* lh = (char*)&sA[buf][1][0] + p * 4096 + wc * 1024;
      gl_lds16(ga + gb, la);
      gl_lds16(gh + gb, lh);
    }
  };

  const int tstep = gridDim.x >> 1;
  int tile = blockIdx.x >> 1;
  if (tile < ntiles) stage(0, tile);
  int cur = 0;

  for (; tile < ntiles; tile += tstep) {
    __syncthreads();   // buf[cur] staged; prev iter's LDS reads done
    int nxt = tile + tstep;
    if (nxt < ntiles) stage(cur ^ 1, nxt);

    const char* cb = (const char*)&sA[cur][0][0];
    f32x4 ar[2], az[2], ain[2], ahn[2];
#pragma unroll
    for (int mt = 0; mt < 2; ++mt) {
      ar[mt] = (f32x4){0.f, 0.f, 0.f, 0.f};
      az[mt] = (f32x4){0.f, 0.f, 0.f, 0.f};
      ain[mt] = (f32x4){0.f, 0.f, 0.f, 0.f};
      ahn[mt] = (f32x4){0.f, 0.f, 0.f, 0.f};
    }

#pragma unroll
    for (int ks = 0; ks < 4; ++ks) {
      bf16x8 aa[2], ah[2];
#pragma unroll
      for (int mt = 0; mt < 2; ++mt) {
        int row = mt * 16 + (lane & 15);
        int ch  = (ks * 4 + (lane >> 4)) ^ (row & 7);
        aa[mt] = *(const bf16x8*)(cb + row * 256 + ch * 16);
        ah[mt] = *(const bf16x8*)(cb + 8192 + row * 256 + ch * 16);
      }
#pragma unroll
      for (int mt = 0; mt < 2; ++mt) {
        ar[mt]  = __builtin_amdgcn_mfma_f32_16x16x32_bf16(aa[mt], w[ks],      ar[mt], 0, 0, 0);
        ar[mt]  = __builtin_amdgcn_mfma_f32_16x16x32_bf16(ah[mt], w[4 + ks],  ar[mt], 0, 0, 0);
        az[mt]  = __builtin_amdgcn_mfma_f32_16x16x32_bf16(aa[mt], w[8 + ks],  az[mt], 0, 0, 0);
        az[mt]  = __builtin_amdgcn_mfma_f32_16x16x32_bf16(ah[mt], w[12 + ks], az[mt], 0, 0, 0);
        ain[mt] = __builtin_amdgcn_mfma_f32_16x16x32_bf16(aa[mt], w[16 + ks], ain[mt], 0, 0, 0);
        ahn[mt] = __builtin_amdgcn_mfma_f32_16x16x32_bf16(ah[mt], w[20 + ks], ahn[mt], 0, 0, 0);
      }
    }

    // epilogue: h' = (1-z)*tanh(in + r*hn) + z*h_old ; h_old from LDS h-tile
    const __hip_bfloat16* hbase = &sA[cur][1][0];
    int row0 = tile * 32;
#pragma unroll
    for (int mt = 0; mt < 2; ++mt) {
#pragma unroll
      for (int j = 0; j < 4; ++j) {
        int lr = mt * 16 + (lane >> 4) * 4 + j;
        int grow = row0 + lr;
        if (grow < n) {
          float r  = 1.f / (1.f + __expf(-(ar[mt][j] + br)));
          float z  = 1.f / (1.f + __expf(-(az[mt][j] + bz)));
          float pa = ain[mt][j] + bin + r * (ahn[mt][j] + bhn);
          float e2 = __expf(2.f * pa);
          float nn = 1.f - 2.f / (e2 + 1.f);   // tanh, branch-free
          int ch2 = (col >> 3) ^ (lr & 7);
          float hold = __bfloat162float(hbase[lr * 128 + ch2 * 8 + (col & 7)]);
          float o = (1.f - z) * nn + z * hold;
          hb[(size_t)grow * 128 + col] = __float2bfloat16(o);
        }
      }
    }
    cur ^= 1;
  }
}

// ---------- per-node 1/max(||h||,eps) over bf16 state ----------
__global__ void k_norm(const __hip_bfloat16* __restrict__ hb, float* __restrict__ rnorm,
                       int n) {
  int node = (blockIdx.x * THREADS + threadIdx.x) >> 6;
  int lane = threadIdx.x & 63;
  if (node >= n) return;
  unsigned v = ((const unsigned*)hb)[(size_t)node * 64 + lane];
  float a = bf_lo(v), b = bf_hi(v);
  float s = a * a + b * b;
#pragma unroll
  for (int d = 1; d < 64; d <<= 1) s += __shfl_xor(s, d);
  if (lane == 0) rnorm[node] = 1.f / fmaxf(sqrtf(s), 1e-12f);
}

// ---------- per-graph max/mean pool of relu(hb * rnorm), split POOLS ways ----------
__global__ void k_pool(const __hip_bfloat16* __restrict__ hb, const float* __restrict__ rnorm,
                       const int* __restrict__ gs, const int* __restrict__ ge,
                       float* __restrict__ featp) {
  int g = blockIdx.x, sp = blockIdx.y;
  int c = threadIdx.x;  // 128
  int s = gs[g], e = ge[g];
  int len = e - s;
  int chunk = (len + POOLS - 1) / POOLS;
  int ns = s + sp * chunk;
  int ne = ns + chunk; if (ne > e) ne = e;
  float mx = 0.f, sm = 0.f;
  for (int nd = ns; nd < ne; ++nd) {
    float v = __bfloat162float(hb[(size_t)nd * 128 + c]) * rnorm[nd];
    v = fmaxf(v, 0.f);
    mx = fmaxf(mx, v);
    sm += v;
  }
  featp[((size_t)g * POOLS + sp) * 256 + c]       = mx;
  featp[((size_t)g * POOLS + sp) * 256 + 128 + c] = sm;
}

__global__ void k_pool2(const float* __restrict__ featp, const int* __restrict__ gs,
                        const int* __restrict__ ge, float* __restrict__ feat) {
  int g = blockIdx.x;
  int c = threadIdx.x;  // 256
  float mx = 0.f, sm = 0.f;
  for (int sp = 0; sp < POOLS; ++sp) {
    float v = featp[((size_t)g * POOLS + sp) * 256 + c];
    mx = fmaxf(mx, v);
    sm += v;
  }
  float cnt = fmaxf((float)(ge[g] - gs[g]), 1.f);
  feat[(size_t)g * 256 + c] = (c < 128) ? mx : (sm / cnt);
}

// ---------- final linear ----------
__global__ void k_final(const float* __restrict__ feat, const float* __restrict__ lin_w,
                        const float* __restrict__ lin_b, float* __restrict__ out) {
  int g = blockIdx.x;
  __shared__ float sf[256];
  sf[threadIdx.x] = feat[(size_t)g * 256 + threadIdx.x];
  __syncthreads();
  if (threadIdx.x < 10) {
    float s = lin_b[threadIdx.x];
    const float* w = lin_w + (size_t)threadIdx.x * 256;
#pragma unroll 8
    for (int c = 0; c < 256; ++c) s += sf[c] * w[c];
    out[(size_t)g * 10 + threadIdx.x] = s;
  }
}

extern "C" void kernel_launch(void* const* d_in, const int* in_sizes, int n_in,
                              void* d_out, int out_size, void* d_ws, size_t ws_size,
                              hipStream_t stream) {
  const float* x      = (const float*)d_in[0];
  const int*   ei     = (const int*)d_in[1];
  const int*   batch  = (const int*)d_in[2];
  const float* weight = (const float*)d_in[3];
  const float* w_ih   = (const float*)d_in[4];
  const float* w_hh   = (const float*)d_in[5];
  const float* b_ih   = (const float*)d_in[6];
  const float* b_hh   = (const float*)d_in[7];
  const float* lin_w  = (const float*)d_in[8];
  const float* lin_b  = (const float*)d_in[9];
  float* out = (float*)d_out;

  const int N = in_sizes[0] / 128;   // 100000
  const int E = in_sizes[1] / 2;     // 1600000
  const int G = out_size / 10;       // 64
  const int NB2 = (N + BK2SZ - 1) / BK2SZ;  // 196 coarse buckets
  const int WP_PER_LAYER = 8 * 24 * 64 * 8;  // 98304

  char* wsc = (char*)d_ws;
  size_t off = 0;
  auto take = [&](size_t bytes) -> void* {
    void* p = wsc + off;
    off = align_up(off + bytes, 256);
    return p;
  };
  __hip_bfloat16*  hb     = (__hip_bfloat16*)take((size_t)N * 128 * 2);
  __hip_bfloat16*  agg    = (__hip_bfloat16*)take((size_t)N * 128 * 2);
  float*           Wc     = (float*)take((size_t)3 * 384 * 128 * 4);
  __hip_bfloat16*  Wp     = (__hip_bfloat16*)take((size_t)3 * WP_PER_LAYER * 2);
  float*           rnorm  = (float*)take((size_t)N * 4);
  int*             offs   = (int*)take(((size_t)N + 1) * 4);
  int*             bcount = (int*)take(256 * 4);
  int*             boffs  = (int*)take(257 * 4);
  int*             bcursor= (int*)take(256 * 4);
  int*             csr    = (int*)take((size_t)E * 4);
  int*             gs     = (int*)take((size_t)G * 4);
  int*             ge     = (int*)take((size_t)G * 4);
  float*           featp  = (float*)take((size_t)G * POOLS * 256 * 4);
  float*           feat   = (float*)take((size_t)G * 256 * 4);
  int*             flag   = (int*)take(256);
  int*             scratch = (int*)agg;   // agg not live during CSR build
  (void)ws_size; (void)n_in;

  hipMemsetAsync(bcount, 0, 256 * 4, stream);
  hipMemsetAsync(gs, 0, (size_t)G * 4, stream);
  hipMemsetAsync(ge, 0, (size_t)G * 4, stream);

  k_detect<<<1, 64, 0, stream>>>(ei, flag);
  k_wc<<<(3 * 384 * 128 + THREADS - 1) / THREADS, THREADS, 0, stream>>>(weight, w_ih, Wc);
  k_wprep<<<(3 * WP_PER_LAYER + THREADS - 1) / THREADS, THREADS, 0, stream>>>(Wc, w_hh, Wp);
  k_init<<<(N * 32 + THREADS - 1) / THREADS, THREADS, 0, stream>>>(x, hb, N * 32);

  // two-level CSR build
  k_bhist<<<128, THREADS, 0, stream>>>(ei, bcount, E, NB2, flag);
  k_bscan<<<1, 256, 0, stream>>>(bcount, boffs, bcursor, NB2, E);
  k_bscatter<<<(E + CHUNK - 1) / CHUNK, THREADS, 0, stream>>>(ei, bcursor, scratch, E, flag);
  k_bcsr<<<NB2, THREADS, 0, stream>>>(scratch, boffs, offs, csr, N, NB2, E);
  k_bounds<<<(N + 255) / 256, 256, 0, stream>>>(batch, gs, ge, N, flag);

  const int ntiles = (N + 31) / 32;  // 3125
  for (int layer = 0; layer < 3; ++layer) {
    k_agg<<<(N + 3) / 4, THREADS, 0, stream>>>(hb, offs, csr, agg, N);
    k_gru_pers<<<512, 256, 0, stream>>>(
        agg, hb, Wp + (size_t)layer * WP_PER_LAYER, b_ih, b_hh, N, ntiles);
  }

  k_norm<<<(N + 3) / 4, THREADS, 0, stream>>>(hb, rnorm, N);
  k_pool<<<dim3(G, POOLS), 128, 0, stream>>>(hb, rnorm, gs, ge, featp);
  k_pool2<<<G, 256, 0, stream>>>(featp, gs, ge, feat);
  k_final<<<G, 256, 0, stream>>>(feat, lin_w, lin_b, out);
}